// Round 2
// baseline (3356.396 us; speedup 1.0000x reference)
//
#include <hip/hip_runtime.h>
#include <hip/hip_cooperative_groups.h>

namespace cg = cooperative_groups;

// WaveNet on gfx950, fp16 MFMA path, round 7.
// r5: 22 serial dispatches, all pipes ~10% busy -> serialization-bound (798us).
// r6: dataflow flag protocol with hand-rolled sc0/sc1 coherence -> absmax 0.72
//     (race in the custom release/acquire chain; window arithmetic audited OK).
// r7: SAME single persistent kernel, but lockstep phases with cooperative
//     grid.sync() (runtime-supplied device-scope fences, documented-supported).
//     No flags, no sc0/sc1, plain cached loads/stores -> numerics == r5.
//     Co-residency: launch_bounds(256,4) caps VGPR at 128, LDS 34816 ->
//     4 blocks/CU * 256 CU = 1024 blocks = grid size exactly.
//     Fallback: if cooperative launch fails, classic 22-dispatch path (~r5).

#define TT 8192
#define HIDC 128
#define GOODC 2046
#define TGT 6146
#define NL 20

typedef _Float16 half8_t __attribute__((ext_vector_type(8)));
typedef _Float16 half4_t __attribute__((ext_vector_type(4)));
typedef float floatx4 __attribute__((ext_vector_type(4)));

__device__ __forceinline__ floatx4 mfma16(half8_t a, half8_t b, floatx4 c) {
  return __builtin_amdgcn_mfma_f32_16x16x32_f16(a, b, c, 0, 0, 0);
}

__device__ __forceinline__ float fast_sigmoid(float x) {
  return __builtin_amdgcn_rcpf(1.0f + __expf(-x));
}
__device__ __forceinline__ float fast_tanh(float x) {
  return 2.0f * __builtin_amdgcn_rcpf(1.0f + __expf(-2.0f * x)) - 1.0f;
}

// ---------------- weight prep: fp32 -> fp16, stacked layouts ----------------
__global__ void prep_kernel(const float* __restrict__ Wi, const float* __restrict__ Wf,
                            const float* __restrict__ Wg, const float* __restrict__ Wr,
                            const float* __restrict__ W1, const float* __restrict__ W2,
                            _Float16* __restrict__ WIh, _Float16* __restrict__ WFG,
                            _Float16* __restrict__ WRh, _Float16* __restrict__ W1h,
                            _Float16* __restrict__ W2h) {
  int idx = blockIdx.x * blockDim.x + threadIdx.x;
  int stride = gridDim.x * blockDim.x;
  // WFG[l][m][k]: m<128 -> Wf row m, else Wg row m-128; k<128 -> tap0 (u-d), else tap1 (u)
  for (int i = idx; i < NL * 256 * 256; i += stride) {
    int l = i >> 16; int m = (i >> 8) & 255; int k = i & 255;
    int tap = k >> 7; int ci = k & 127;
    float v;
    if (m < 128) v = Wf[(((size_t)l * 128 + m) * 128 + ci) * 2 + tap];
    else         v = Wg[(((size_t)l * 128 + (m - 128)) * 128 + ci) * 2 + tap];
    WFG[i] = (_Float16)v;
  }
  for (int i = idx; i < NL * 128 * 128; i += stride) WRh[i] = (_Float16)Wr[i];
  for (int i = idx; i < 128 * 256; i += stride) WIh[i] = (_Float16)Wi[i];
  for (int i = idx; i < 512 * 128; i += stride) W1h[i] = (_Float16)W1[i];
  for (int i = idx; i < 256 * 512; i += stride) W2h[i] = (_Float16)W2[i];
}

// ---------------- phase 0: input 1x1 conv for one 64-pos tile ----------------
__device__ __forceinline__ void phase_input(
    const float* __restrict__ ib, const _Float16* __restrict__ WIh,
    const float* __restrict__ bi, _Float16* __restrict__ Rb, int u0,
    char* smem) {
  _Float16(*Xs)[264] = (_Float16(*)[264])smem;
  const int tid = threadIdx.x;
  const int lane = tid & 63;
  const int w = tid >> 6;
  const int ml = lane & 15;
  const int mq = lane >> 4;

#pragma unroll
  for (int it = 0; it < 4; ++it) {
    int i = it * 256 + tid;
    int n4 = i & 15;
    int kg = i >> 4;
    const float* src = ib + (size_t)(kg * 4) * TT + u0 + n4 * 4;
    floatx4 c0 = *(const floatx4*)(src);
    floatx4 c1 = *(const floatx4*)(src + TT);
    floatx4 c2 = *(const floatx4*)(src + 2 * TT);
    floatx4 c3 = *(const floatx4*)(src + 3 * TT);
#pragma unroll
    for (int tq = 0; tq < 4; ++tq) {
      half4_t h;
      h[0] = (_Float16)c0[tq]; h[1] = (_Float16)c1[tq];
      h[2] = (_Float16)c2[tq]; h[3] = (_Float16)c3[tq];
      *(half4_t*)&Xs[n4 * 4 + tq][kg * 4] = h;
    }
  }
  __syncthreads();

  floatx4 acc[2][4];
#pragma unroll
  for (int a = 0; a < 2; ++a)
#pragma unroll
    for (int c = 0; c < 4; ++c) acc[a][c] = floatx4{0.f, 0.f, 0.f, 0.f};

  const _Float16* Aw = WIh + (size_t)(32 * w + ml) * 256;
#pragma unroll
  for (int kk = 0; kk < 8; ++kk) {
    const int ko = kk * 32 + mq * 8;
    half8_t a0 = *(const half8_t*)(Aw + ko);
    half8_t a1 = *(const half8_t*)(Aw + 16 * 256 + ko);
#pragma unroll
    for (int nt = 0; nt < 4; ++nt) {
      half8_t bv = *(const half8_t*)&Xs[nt * 16 + ml][ko];
      acc[0][nt] = mfma16(a0, bv, acc[0][nt]);
      acc[1][nt] = mfma16(a1, bv, acc[1][nt]);
    }
  }
  __syncthreads();
  float* Xf = (float*)smem;
#pragma unroll
  for (int mt = 0; mt < 2; ++mt) {
    const int mb = 32 * w + mt * 16 + mq * 4;
#pragma unroll
    for (int nt = 0; nt < 4; ++nt)
      *(floatx4*)&Xf[(nt * 16 + ml) * 132 + mb] = acc[mt][nt];
  }
  __syncthreads();
#pragma unroll
  for (int it = 0; it < 4; ++it) {
    int i = it * 256 + tid;
    int n = i >> 4; int cq = i & 15;
    floatx4 x0 = *(const floatx4*)&Xf[n * 132 + cq * 8];
    floatx4 x1 = *(const floatx4*)&Xf[n * 132 + cq * 8 + 4];
    floatx4 b0 = *(const floatx4*)(bi + cq * 8);
    floatx4 b1v = *(const floatx4*)(bi + cq * 8 + 4);
    half8_t h;
#pragma unroll
    for (int tq = 0; tq < 4; ++tq) {
      h[tq] = (_Float16)(x0[tq] + b0[tq]);
      h[4 + tq] = (_Float16)(x1[tq] + b1v[tq]);
    }
    *(half8_t*)(Rb + (size_t)(u0 + n) * HIDC + cq * 8) = h;
  }
  __syncthreads();  // smem dead before caller reuses it
}

// ---------------- phases 1..20: one residual layer for one tile -------------
__device__ __forceinline__ void phase_layer(
    const _Float16* __restrict__ Rb, _Float16* __restrict__ Ro,
    const _Float16* __restrict__ WFGl, const _Float16* __restrict__ WRl,
    const float* __restrict__ bfl, const float* __restrict__ bgl,
    const float* __restrict__ brl, int d, int u0, char* smem) {
  _Float16(*Xs0)[136] = (_Float16(*)[136])smem;            // tap0; later Os
  _Float16(*Xs1)[136] = (_Float16(*)[136])(smem + 17408);  // tap1 = R_old
  const int tid = threadIdx.x;
  const int lane = tid & 63;
  const int w = tid >> 6;
  const int ml = lane & 15;
  const int mq = lane >> 4;

  // ---- stage both taps (2048 x 16B chunks, 8 per thread), 1 barrier ----
#pragma unroll
  for (int it = 0; it < 8; ++it) {
    int i = it * 256 + tid;          // n(6b) | tap(1b) | c(4b)
    int c = i & 15;
    int tap = (i >> 4) & 1;
    int n = i >> 5;
    int u = u0 + n - (tap ? 0 : d);
    if (u < 0) u = 0;                // below-valid garbage is never consumed
    _Float16* dst = tap ? &Xs1[n][c * 8] : &Xs0[n][c * 8];
    *(half8_t*)dst = *(const half8_t*)(Rb + (size_t)u * HIDC + c * 8);
  }
  __syncthreads();  // b1

  // ---- GEMM1: [f;g](256 rows) x K=256; wave w owns f-rows & g-rows [32w,32w+32) ----
  floatx4 accF[2][4], accG[2][4];
#pragma unroll
  for (int a = 0; a < 2; ++a)
#pragma unroll
    for (int cc = 0; cc < 4; ++cc) {
      accF[a][cc] = floatx4{0.f, 0.f, 0.f, 0.f};
      accG[a][cc] = floatx4{0.f, 0.f, 0.f, 0.f};
    }
  const _Float16* Af = WFGl + (size_t)(32 * w + ml) * 256;
  const _Float16* Ag = Af + 128 * 256;
#pragma unroll
  for (int h = 0; h < 2; ++h) {
    const _Float16(*X)[136] = h ? Xs1 : Xs0;
#pragma unroll
    for (int kk = 0; kk < 4; ++kk) {
      const int ko = kk * 32 + mq * 8;   // [0,128) LDS col
      const int kw = h * 128 + ko;       // weight col
      half8_t aF0 = *(const half8_t*)(Af + kw);
      half8_t aF1 = *(const half8_t*)(Af + 16 * 256 + kw);
      half8_t aG0 = *(const half8_t*)(Ag + kw);
      half8_t aG1 = *(const half8_t*)(Ag + 16 * 256 + kw);
#pragma unroll
      for (int nt = 0; nt < 4; ++nt) {
        half8_t bv = *(const half8_t*)&X[nt * 16 + ml][ko];
        accF[0][nt] = mfma16(aF0, bv, accF[0][nt]);
        accF[1][nt] = mfma16(aF1, bv, accF[1][nt]);
        accG[0][nt] = mfma16(aG0, bv, accG[0][nt]);
        accG[1][nt] = mfma16(aG1, bv, accG[1][nt]);
      }
    }
  }

  // ---- gate in registers ----
  half4_t og[2][4];
#pragma unroll
  for (int mt = 0; mt < 2; ++mt) {
    const int mb = 32 * w + mt * 16 + mq * 4;
    floatx4 bfv = *(const floatx4*)(bfl + mb);
    floatx4 bgv = *(const floatx4*)(bgl + mb);
#pragma unroll
    for (int nt = 0; nt < 4; ++nt) {
#pragma unroll
      for (int r = 0; r < 4; ++r) {
        float fv = fast_tanh(accF[mt][nt][r] + bfv[r]);
        float gv = fast_sigmoid(accG[mt][nt][r] + bgv[r]);
        og[mt][nt][r] = (_Float16)(fv * gv);
      }
    }
  }
  __syncthreads();  // b2: all Xs0 reads complete -> reuse as Os

  _Float16(*Os)[136] = Xs0;
#pragma unroll
  for (int mt = 0; mt < 2; ++mt) {
    const int mb = 32 * w + mt * 16 + mq * 4;
#pragma unroll
    for (int nt = 0; nt < 4; ++nt)
      *(half4_t*)&Os[nt * 16 + ml][mb] = og[mt][nt];
  }
  __syncthreads();  // b3: Os visible

  // ---- GEMM2: x = WR(128x128) @ out ----
  floatx4 accX[2][4];
#pragma unroll
  for (int a = 0; a < 2; ++a)
#pragma unroll
    for (int cc = 0; cc < 4; ++cc) accX[a][cc] = floatx4{0.f, 0.f, 0.f, 0.f};
  const _Float16* Ar = WRl + (size_t)(32 * w + ml) * 128;
#pragma unroll
  for (int kk = 0; kk < 4; ++kk) {
    const int ko = kk * 32 + mq * 8;
    half8_t a0 = *(const half8_t*)(Ar + ko);
    half8_t a1 = *(const half8_t*)(Ar + 16 * 128 + ko);
#pragma unroll
    for (int nt = 0; nt < 4; ++nt) {
      half8_t bv = *(const half8_t*)&Os[nt * 16 + ml][ko];
      accX[0][nt] = mfma16(a0, bv, accX[0][nt]);
      accX[1][nt] = mfma16(a1, bv, accX[1][nt]);
    }
  }

  // ---- register epilogue: R_new = x + br + R_old (from Xs1) ----
  half4_t xo[2][4];
#pragma unroll
  for (int mt = 0; mt < 2; ++mt) {
    const int mb = 32 * w + mt * 16 + mq * 4;
    floatx4 brv = *(const floatx4*)(brl + mb);
#pragma unroll
    for (int nt = 0; nt < 4; ++nt) {
      const int n = nt * 16 + ml;
      half4_t rold = *(const half4_t*)&Xs1[n][mb];
#pragma unroll
      for (int r = 0; r < 4; ++r)
        xo[mt][nt][r] = (_Float16)(accX[mt][nt][r] + brv[r] + (float)rold[r]);
    }
  }
  __syncthreads();  // b4: all Os + Xs1 reads complete

#pragma unroll
  for (int mt = 0; mt < 2; ++mt) {
    const int mb = 32 * w + mt * 16 + mq * 4;
#pragma unroll
    for (int nt = 0; nt < 4; ++nt)
      *(half4_t*)&Os[nt * 16 + ml][mb] = xo[mt][nt];
  }
  __syncthreads();  // b5

  // ---- coalesced store: 16B/lane, row-contiguous ----
#pragma unroll
  for (int it = 0; it < 4; ++it) {
    int i = it * 256 + tid;
    int n = i >> 4, c = i & 15;
    *(half8_t*)(Ro + (size_t)(u0 + n) * HIDC + c * 8) = *(const half8_t*)&Os[n][c * 8];
  }
  __syncthreads();  // smem dead before caller reuses it
}

// ---------------- phase 21: head for one tile --------------------------------
__device__ __forceinline__ void phase_head(
    const _Float16* __restrict__ Ra, const _Float16* __restrict__ Rz,
    const _Float16* __restrict__ W1h, const _Float16* __restrict__ W2h,
    const float* __restrict__ b1, const float* __restrict__ b2,
    float* __restrict__ outb, int u0, char* smem) {
  _Float16* Hs = (_Float16*)smem;              // [64][136]
  _Float16* H1s = (_Float16*)(smem + 17408);   // [64][136]
  const int tid = threadIdx.x;
  const int lane = tid & 63;
  const int w = tid >> 6;
  const int ml = lane & 15;
  const int mq = lane >> 4;

  // stage relu(Rfin - R0)
#pragma unroll
  for (int it = 0; it < 4; ++it) {
    int i = it * 256 + tid;
    int n = i >> 4; int cq = i & 15;
    int u = u0 + n;   // u0 <= 8128, n <= 63 -> u < TT always
    half8_t a = *(const half8_t*)(Ra + (size_t)u * HIDC + cq * 8);
    half8_t z = *(const half8_t*)(Rz + (size_t)u * HIDC + cq * 8);
    half8_t h;
#pragma unroll
    for (int tq = 0; tq < 8; ++tq) {
      float v = (float)a[tq] - (float)z[tq];
      h[tq] = (_Float16)(v > 0.f ? v : 0.f);
    }
    *(half8_t*)&Hs[n * 136 + cq * 8] = h;
  }
  __syncthreads();

  floatx4 accO[4][4];  // wave w out-rows [64w,64w+64): m = 64w+16mt+4mq+r, n = 16nt+ml
#pragma unroll
  for (int a = 0; a < 4; ++a)
#pragma unroll
    for (int c = 0; c < 4; ++c) accO[a][c] = floatx4{0.f, 0.f, 0.f, 0.f};

  for (int p = 0; p < 4; ++p) {
    floatx4 acc1[2][4];
#pragma unroll
    for (int a = 0; a < 2; ++a)
#pragma unroll
      for (int c = 0; c < 4; ++c) acc1[a][c] = floatx4{0.f, 0.f, 0.f, 0.f};
    const _Float16* A1 = W1h + (size_t)(128 * p + 32 * w + ml) * 128;
#pragma unroll
    for (int kk = 0; kk < 4; ++kk) {
      const int ko = kk * 32 + mq * 8;
      half8_t av0 = *(const half8_t*)(A1 + ko);
      half8_t av1 = *(const half8_t*)(A1 + 16 * 128 + ko);
#pragma unroll
      for (int nt = 0; nt < 4; ++nt) {
        half8_t bv = *(const half8_t*)&Hs[(nt * 16 + ml) * 136 + ko];
        acc1[0][nt] = mfma16(av0, bv, acc1[0][nt]);
        acc1[1][nt] = mfma16(av1, bv, acc1[1][nt]);
      }
    }
    __syncthreads();  // previous pass's H1s reads complete
#pragma unroll
    for (int mt = 0; mt < 2; ++mt) {
      const int kc = 32 * w + mt * 16 + mq * 4;
      floatx4 bv = *(const floatx4*)(b1 + 128 * p + kc);
#pragma unroll
      for (int nt = 0; nt < 4; ++nt) {
        half4_t h;
#pragma unroll
        for (int r = 0; r < 4; ++r) {
          float v = acc1[mt][nt][r] + bv[r];
          h[r] = (_Float16)(v > 0.f ? v : 0.f);
        }
        *(half4_t*)&H1s[(nt * 16 + ml) * 136 + kc] = h;
      }
    }
    __syncthreads();
    const _Float16* A2 = W2h + (size_t)(64 * w + ml) * 512 + p * 128;
#pragma unroll
    for (int kk = 0; kk < 4; ++kk) {
      const int ko = kk * 32 + mq * 8;
#pragma unroll
      for (int nt = 0; nt < 4; ++nt) {
        half8_t bv = *(const half8_t*)&H1s[(nt * 16 + ml) * 136 + ko];
#pragma unroll
        for (int mt = 0; mt < 4; ++mt) {
          half8_t av = *(const half8_t*)(A2 + (size_t)(mt * 16) * 512 + ko);
          accO[mt][nt] = mfma16(av, bv, accO[mt][nt]);
        }
      }
    }
    __syncthreads();  // H1s reads done before next pass overwrites (and before alias)
  }

  _Float16* Ot = (_Float16*)smem;  // [64][264]
#pragma unroll
  for (int mt = 0; mt < 4; ++mt) {
    const int m = 64 * w + mt * 16 + mq * 4;
    floatx4 bv = *(const floatx4*)(b2 + m);
#pragma unroll
    for (int nt = 0; nt < 4; ++nt) {
      const int n = nt * 16 + ml;
      half4_t h;
#pragma unroll
      for (int r = 0; r < 4; ++r) h[r] = (_Float16)(accO[mt][nt][r] + bv[r]);
      *(half4_t*)&Ot[n * 264 + m] = h;
    }
  }
  __syncthreads();
#pragma unroll
  for (int it = 0; it < 8; ++it) {
    int i = it * 256 + tid;
    int n = i >> 5;
    int g = i & 31;
    int u = u0 + n;
    if (u >= GOODC) {  // u < TT always
      half8_t v = *(const half8_t*)&Ot[n * 264 + g * 8];
      float* dst = outb + (size_t)(u - GOODC) * 256 + g * 8;
      floatx4 v0, v1;
#pragma unroll
      for (int tq = 0; tq < 4; ++tq) { v0[tq] = (float)v[tq]; v1[tq] = (float)v[4 + tq]; }
      *(floatx4*)dst = v0;
      *(floatx4*)(dst + 4) = v1;
    }
  }
}

// ---------------- persistent lockstep kernel (cooperative) -------------------
__global__ __launch_bounds__(256, 4) void mega_kernel(
    const float* __restrict__ inp, const _Float16* __restrict__ WIh,
    const float* __restrict__ bi, const _Float16* __restrict__ WFG,
    const _Float16* __restrict__ WRh, const float* __restrict__ bf,
    const float* __restrict__ bg, const float* __restrict__ br,
    const _Float16* __restrict__ W1h, const _Float16* __restrict__ W2h,
    const float* __restrict__ b1, const float* __restrict__ b2,
    _Float16* __restrict__ R0h, _Float16* __restrict__ Ph,
    _Float16* __restrict__ Qh, float* __restrict__ out) {
  __shared__ __align__(16) char smem[34816];
  cg::grid_group grid = cg::this_grid();
  const int bb = blockIdx.x >> 7;   // batch
  const int j = blockIdx.x & 127;   // 64-pos tile within batch
  const int u0 = j * 64;

  phase_input(inp + (size_t)bb * 256 * TT, WIh, bi,
              R0h + (size_t)bb * TT * HIDC, u0, smem);
  grid.sync();

#pragma unroll 1
  for (int l = 0; l < NL; ++l) {
    const int d = 1 << (l % 10);
    const _Float16* rin = (l == 0) ? R0h : ((l & 1) ? Ph : Qh);
    _Float16* rout = (l & 1) ? Qh : Ph;
    phase_layer(rin + (size_t)bb * TT * HIDC, rout + (size_t)bb * TT * HIDC,
                WFG + (size_t)l * 65536, WRh + (size_t)l * 16384,
                bf + l * 128, bg + l * 128, br + l * 128, d, u0, smem);
    grid.sync();
  }

  // after l=19 (odd), final res is in Qh; head only for tiles reaching u>=GOODC
  if (j >= 31)
    phase_head(Qh + (size_t)bb * TT * HIDC, R0h + (size_t)bb * TT * HIDC,
               W1h, W2h, b1, b2, out + (size_t)bb * TGT * 256, u0, smem);
}

// ---------------- fallback wrappers (classic 22-dispatch path) ---------------
__global__ __launch_bounds__(256, 3) void input_k(
    const float* __restrict__ inp, const _Float16* __restrict__ WIh,
    const float* __restrict__ bi, _Float16* __restrict__ R0h) {
  __shared__ __align__(16) char smem[34816];
  phase_input(inp + (size_t)blockIdx.y * 256 * TT, WIh, bi,
              R0h + (size_t)blockIdx.y * TT * HIDC, blockIdx.x * 64, smem);
}
__global__ __launch_bounds__(256, 3) void layer_k(
    const _Float16* __restrict__ rin, _Float16* __restrict__ rout,
    const _Float16* __restrict__ WFGl, const _Float16* __restrict__ WRl,
    const float* __restrict__ bfl, const float* __restrict__ bgl,
    const float* __restrict__ brl, int d) {
  __shared__ __align__(16) char smem[34816];
  phase_layer(rin + (size_t)blockIdx.y * TT * HIDC,
              rout + (size_t)blockIdx.y * TT * HIDC,
              WFGl, WRl, bfl, bgl, brl, d, blockIdx.x * 64, smem);
}
__global__ __launch_bounds__(256, 3) void head_k(
    const _Float16* __restrict__ Ra, const _Float16* __restrict__ Rz,
    const _Float16* __restrict__ W1h, const _Float16* __restrict__ W2h,
    const float* __restrict__ b1, const float* __restrict__ b2,
    float* __restrict__ out) {
  __shared__ __align__(16) char smem[34816];
  phase_head(Ra + (size_t)blockIdx.y * TT * HIDC,
             Rz + (size_t)blockIdx.y * TT * HIDC,
             W1h, W2h, b1, b2, out + (size_t)blockIdx.y * TGT * 256,
             (31 + blockIdx.x) * 64, smem);
}

extern "C" void kernel_launch(void* const* d_in, const int* in_sizes, int n_in,
                              void* d_out, int out_size, void* d_ws, size_t ws_size,
                              hipStream_t stream) {
  const float* inputs = (const float*)d_in[0];
  const float* Wi = (const float*)d_in[1];
  const float* bi = (const float*)d_in[2];
  const float* Wf = (const float*)d_in[3];
  const float* bf = (const float*)d_in[4];
  const float* Wg = (const float*)d_in[5];
  const float* bg = (const float*)d_in[6];
  const float* Wr = (const float*)d_in[7];
  const float* br = (const float*)d_in[8];
  const float* W1 = (const float*)d_in[9];
  const float* b1 = (const float*)d_in[10];
  const float* W2 = (const float*)d_in[11];
  const float* b2 = (const float*)d_in[12];
  float* out = (float*)d_out;

  // workspace layout (~54 MB): three fp16 res buffers + fp16 weights
  char* ws = (char*)d_ws;
  _Float16* R0h = (_Float16*)(ws + 0);
  _Float16* Ph  = (_Float16*)(ws + 16777216);
  _Float16* Qh  = (_Float16*)(ws + 33554432);
  _Float16* WFG = (_Float16*)(ws + 50331648);
  _Float16* WRh = (_Float16*)(ws + 52953088);
  _Float16* WIh = (_Float16*)(ws + 53608448);
  _Float16* W1h = (_Float16*)(ws + 53673984);
  _Float16* W2h = (_Float16*)(ws + 53805056);

  prep_kernel<<<dim3(512), dim3(256), 0, stream>>>(Wi, Wf, Wg, Wr, W1, W2,
                                                   WIh, WFG, WRh, W1h, W2h);

  void* kargs[] = {(void*)&inputs, (void*)&WIh, (void*)&bi,  (void*)&WFG,
                   (void*)&WRh,    (void*)&bf,  (void*)&bg,  (void*)&br,
                   (void*)&W1h,    (void*)&W2h, (void*)&b1,  (void*)&b2,
                   (void*)&R0h,    (void*)&Ph,  (void*)&Qh,  (void*)&out};
  hipError_t err = hipLaunchCooperativeKernel(
      (const void*)mega_kernel, dim3(1024), dim3(256), kargs, 0, stream);

  if (err != hipSuccess) {
    // classic path: 22 stream-ordered dispatches (== r5 semantics)
    input_k<<<dim3(128, 8), dim3(256), 0, stream>>>(inputs, WIh, bi, R0h);
    for (int l = 0; l < NL; ++l) {
      int d = 1 << (l % 10);
      const _Float16* rin = (l == 0) ? R0h : ((l & 1) ? Ph : Qh);
      _Float16* rout = (l & 1) ? Qh : Ph;
      layer_k<<<dim3(128, 8), dim3(256), 0, stream>>>(
          rin, rout, WFG + (size_t)l * 65536, WRh + (size_t)l * 16384,
          bf + l * 128, bg + l * 128, br + l * 128, d);
    }
    head_k<<<dim3(97, 8), dim3(256), 0, stream>>>(Qh, R0h, W1h, W2h, b1, b2, out);
  }
}

// Round 4
// 1146.166 us; speedup vs baseline: 2.9284x; 2.9284x over previous
//
#include <hip/hip_runtime.h>

// WaveNet on gfx950, fp16 MFMA path, round 9.
// r5: 22 serial dispatches, all pipes ~10% -> 798us (serialization-bound).
// r7: cooperative lockstep grid.sync -> 3356us (each sync = full L2 wb+inv).
// r8: XCD-affine dataflow -> container died twice (hang suspected: unbounded
//     rendezvous spin is the only new hang surface vs r6, which completed).
// r9: r8 made HANG-PROOF. Every spin is iteration-bounded with a sticky
//     g_broken flag: if co-residency or the protocol ever fails, the grid
//     degrades to ungated execution and COMPLETES (wrong numerics, ~100ms)
//     instead of hanging the GPU. Fast path unchanged:
//       - blocks self-assign to their XCD's batch via s_getreg(XCC_ID) +
//         per-XCD slot queues -> producer/consumer always share one L2;
//       - release: plain stores -> s_waitcnt vmcnt(0) -> barrier -> relaxed
//         agent-scope flag (LLC-resolved, strictly slower than the L2 data);
//       - acquire: relaxed agent flag spin (atomic LOAD, no RMW storm) ->
//         barrier -> sc0 (L1-bypass) staging loads from shared L2;
//       - heavy fallback (anomalous dispatch): static map + compiler agent
//         release/acquire fences (correct, r7-slow).
//     Co-residency: 512 blocks, LDS 34816 B -> 4 blocks/CU capacity, need 2.

#define TT 8192
#define HIDC 128
#define GOODC 2046
#define TGT 6146
#define NL 20
#define NTILES 1024   // 8 batches * 128 tiles of 64 positions
#define NPHASE 22     // input + 20 layers + head
#define NBLK 512      // persistent blocks, 2 tiles each
#define GATE_CAP (1 << 18)   // ~40-80ms worst case; normal waits ~3K iters
#define RDV_CAP (1 << 16)    // rendezvous bound; normal ~100 iters

typedef _Float16 half8_t __attribute__((ext_vector_type(8)));
typedef _Float16 half4_t __attribute__((ext_vector_type(4)));
typedef float floatx4 __attribute__((ext_vector_type(4)));

__device__ int g_progress[NTILES];  // completed-phase count per tile
__device__ int g_qhead[8];          // per-XCD slot queues
__device__ int g_arrive;            // startup rendezvous counter
__device__ int g_broken;            // sticky protocol-failure flag

__device__ __forceinline__ floatx4 mfma16(half8_t a, half8_t b, floatx4 c) {
  return __builtin_amdgcn_mfma_f32_16x16x32_f16(a, b, c, 0, 0, 0);
}

__device__ __forceinline__ float fast_sigmoid(float x) {
  return __builtin_amdgcn_rcpf(1.0f + __expf(-x));
}
__device__ __forceinline__ float fast_tanh(float x) {
  return 2.0f * __builtin_amdgcn_rcpf(1.0f + __expf(-2.0f * x)) - 1.0f;
}

// 8 L1-bypass (sc0) 16B loads, one waitcnt. L2 is the coherence point
// (same-XCD producer/consumer by construction in light mode).
__device__ __forceinline__ void cload8(
    const void* p0, const void* p1, const void* p2, const void* p3,
    const void* p4, const void* p5, const void* p6, const void* p7,
    floatx4& r0, floatx4& r1, floatx4& r2, floatx4& r3,
    floatx4& r4, floatx4& r5, floatx4& r6, floatx4& r7) {
  asm volatile(
      "global_load_dwordx4 %0, %8, off sc0\n\t"
      "global_load_dwordx4 %1, %9, off sc0\n\t"
      "global_load_dwordx4 %2, %10, off sc0\n\t"
      "global_load_dwordx4 %3, %11, off sc0\n\t"
      "global_load_dwordx4 %4, %12, off sc0\n\t"
      "global_load_dwordx4 %5, %13, off sc0\n\t"
      "global_load_dwordx4 %6, %14, off sc0\n\t"
      "global_load_dwordx4 %7, %15, off sc0\n\t"
      "s_waitcnt vmcnt(0)"
      : "=&v"(r0), "=&v"(r1), "=&v"(r2), "=&v"(r3),
        "=&v"(r4), "=&v"(r5), "=&v"(r6), "=&v"(r7)
      : "v"(p0), "v"(p1), "v"(p2), "v"(p3),
        "v"(p4), "v"(p5), "v"(p6), "v"(p7)
      : "memory");
}

// ---------------- weight prep: fp32 -> fp16, stacked layouts + flag reset ----
__global__ void prep_kernel(const float* __restrict__ Wi, const float* __restrict__ Wf,
                            const float* __restrict__ Wg, const float* __restrict__ Wr,
                            const float* __restrict__ W1, const float* __restrict__ W2,
                            _Float16* __restrict__ WIh, _Float16* __restrict__ WFG,
                            _Float16* __restrict__ WRh, _Float16* __restrict__ W1h,
                            _Float16* __restrict__ W2h) {
  int idx = blockIdx.x * blockDim.x + threadIdx.x;
  int stride = gridDim.x * blockDim.x;
  for (int i = idx; i < NTILES; i += stride) g_progress[i] = 0;
  for (int i = idx; i < 8; i += stride) g_qhead[i] = 0;
  if (idx == 0) { g_arrive = 0; g_broken = 0; }
  // WFG[l][m][k]: m<128 -> Wf row m, else Wg row m-128; k<128 -> tap0 (u-d), else tap1 (u)
  for (int i = idx; i < NL * 256 * 256; i += stride) {
    int l = i >> 16; int m = (i >> 8) & 255; int k = i & 255;
    int tap = k >> 7; int ci = k & 127;
    float v;
    if (m < 128) v = Wf[(((size_t)l * 128 + m) * 128 + ci) * 2 + tap];
    else         v = Wg[(((size_t)l * 128 + (m - 128)) * 128 + ci) * 2 + tap];
    WFG[i] = (_Float16)v;
  }
  for (int i = idx; i < NL * 128 * 128; i += stride) WRh[i] = (_Float16)Wr[i];
  for (int i = idx; i < 128 * 256; i += stride) WIh[i] = (_Float16)Wi[i];
  for (int i = idx; i < 512 * 128; i += stride) W1h[i] = (_Float16)W1[i];
  for (int i = idx; i < 256 * 512; i += stride) W2h[i] = (_Float16)W2[i];
}

// ---------------- phase 0: input 1x1 conv for one 64-pos tile ----------------
__device__ __forceinline__ void phase_input(
    const float* __restrict__ ib, const _Float16* __restrict__ WIh,
    const float* __restrict__ bi, _Float16* __restrict__ Rb, int u0,
    char* smem) {
  _Float16(*Xs)[264] = (_Float16(*)[264])smem;
  const int tid = threadIdx.x;
  const int lane = tid & 63;
  const int w = tid >> 6;
  const int ml = lane & 15;
  const int mq = lane >> 4;

#pragma unroll
  for (int it = 0; it < 4; ++it) {
    int i = it * 256 + tid;
    int n4 = i & 15;
    int kg = i >> 4;
    const float* src = ib + (size_t)(kg * 4) * TT + u0 + n4 * 4;
    floatx4 c0 = *(const floatx4*)(src);
    floatx4 c1 = *(const floatx4*)(src + TT);
    floatx4 c2 = *(const floatx4*)(src + 2 * TT);
    floatx4 c3 = *(const floatx4*)(src + 3 * TT);
#pragma unroll
    for (int tq = 0; tq < 4; ++tq) {
      half4_t h;
      h[0] = (_Float16)c0[tq]; h[1] = (_Float16)c1[tq];
      h[2] = (_Float16)c2[tq]; h[3] = (_Float16)c3[tq];
      *(half4_t*)&Xs[n4 * 4 + tq][kg * 4] = h;
    }
  }
  __syncthreads();

  floatx4 acc[2][4];
#pragma unroll
  for (int a = 0; a < 2; ++a)
#pragma unroll
    for (int c = 0; c < 4; ++c) acc[a][c] = floatx4{0.f, 0.f, 0.f, 0.f};

  const _Float16* Aw = WIh + (size_t)(32 * w + ml) * 256;
#pragma unroll
  for (int kk = 0; kk < 8; ++kk) {
    const int ko = kk * 32 + mq * 8;
    half8_t a0 = *(const half8_t*)(Aw + ko);
    half8_t a1 = *(const half8_t*)(Aw + 16 * 256 + ko);
#pragma unroll
    for (int nt = 0; nt < 4; ++nt) {
      half8_t bv = *(const half8_t*)&Xs[nt * 16 + ml][ko];
      acc[0][nt] = mfma16(a0, bv, acc[0][nt]);
      acc[1][nt] = mfma16(a1, bv, acc[1][nt]);
    }
  }
  __syncthreads();
  float* Xf = (float*)smem;
#pragma unroll
  for (int mt = 0; mt < 2; ++mt) {
    const int mb = 32 * w + mt * 16 + mq * 4;
#pragma unroll
    for (int nt = 0; nt < 4; ++nt)
      *(floatx4*)&Xf[(nt * 16 + ml) * 132 + mb] = acc[mt][nt];
  }
  __syncthreads();
#pragma unroll
  for (int it = 0; it < 4; ++it) {
    int i = it * 256 + tid;
    int n = i >> 4; int cq = i & 15;
    floatx4 x0 = *(const floatx4*)&Xf[n * 132 + cq * 8];
    floatx4 x1 = *(const floatx4*)&Xf[n * 132 + cq * 8 + 4];
    floatx4 b0 = *(const floatx4*)(bi + cq * 8);
    floatx4 b1v = *(const floatx4*)(bi + cq * 8 + 4);
    half8_t h;
#pragma unroll
    for (int tq = 0; tq < 4; ++tq) {
      h[tq] = (_Float16)(x0[tq] + b0[tq]);
      h[4 + tq] = (_Float16)(x1[tq] + b1v[tq]);
    }
    *(half8_t*)(Rb + (size_t)(u0 + n) * HIDC + cq * 8) = h;
  }
  __syncthreads();  // smem dead before caller reuses it
}

// ---------------- phases 1..20: one residual layer for one tile -------------
__device__ __forceinline__ void phase_layer(
    const _Float16* __restrict__ Rb, _Float16* __restrict__ Ro,
    const _Float16* __restrict__ WFGl, const _Float16* __restrict__ WRl,
    const float* __restrict__ bfl, const float* __restrict__ bgl,
    const float* __restrict__ brl, int d, int u0, char* smem) {
  _Float16(*Xs0)[136] = (_Float16(*)[136])smem;            // tap0; later Os
  _Float16(*Xs1)[136] = (_Float16(*)[136])(smem + 17408);  // tap1 = R_old
  const int tid = threadIdx.x;
  const int lane = tid & 63;
  const int w = tid >> 6;
  const int ml = lane & 15;
  const int mq = lane >> 4;

  // ---- stage both taps: 8 sc0 16B loads/thread, 1 barrier ----
  const int c = tid & 15;
  const int tap = (tid >> 4) & 1;
  const int nb = tid >> 5;            // base row 0..7, rows step by 8
  const int off = tap ? 0 : d;
  const _Float16* p[8];
#pragma unroll
  for (int it = 0; it < 8; ++it) {
    int u = u0 + it * 8 + nb - off;
    if (u < 0) u = 0;                 // below-valid garbage is never consumed
    p[it] = Rb + (size_t)u * HIDC + c * 8;
  }
  floatx4 r0, r1, r2, r3, r4, r5, r6, r7;
  cload8(p[0], p[1], p[2], p[3], p[4], p[5], p[6], p[7],
         r0, r1, r2, r3, r4, r5, r6, r7);
  _Float16(*Xt)[136] = tap ? Xs1 : Xs0;
  *(floatx4*)&Xt[nb][c * 8] = r0;
  *(floatx4*)&Xt[8 + nb][c * 8] = r1;
  *(floatx4*)&Xt[16 + nb][c * 8] = r2;
  *(floatx4*)&Xt[24 + nb][c * 8] = r3;
  *(floatx4*)&Xt[32 + nb][c * 8] = r4;
  *(floatx4*)&Xt[40 + nb][c * 8] = r5;
  *(floatx4*)&Xt[48 + nb][c * 8] = r6;
  *(floatx4*)&Xt[56 + nb][c * 8] = r7;
  __syncthreads();  // b1

  // ---- GEMM1: [f;g](256 rows) x K=256 ----
  floatx4 accF[2][4], accG[2][4];
#pragma unroll
  for (int a = 0; a < 2; ++a)
#pragma unroll
    for (int cc = 0; cc < 4; ++cc) {
      accF[a][cc] = floatx4{0.f, 0.f, 0.f, 0.f};
      accG[a][cc] = floatx4{0.f, 0.f, 0.f, 0.f};
    }
  const _Float16* Af = WFGl + (size_t)(32 * w + ml) * 256;
  const _Float16* Ag = Af + 128 * 256;
#pragma unroll
  for (int h = 0; h < 2; ++h) {
    const _Float16(*X)[136] = h ? Xs1 : Xs0;
#pragma unroll
    for (int kk = 0; kk < 4; ++kk) {
      const int ko = kk * 32 + mq * 8;
      const int kw = h * 128 + ko;
      half8_t aF0 = *(const half8_t*)(Af + kw);
      half8_t aF1 = *(const half8_t*)(Af + 16 * 256 + kw);
      half8_t aG0 = *(const half8_t*)(Ag + kw);
      half8_t aG1 = *(const half8_t*)(Ag + 16 * 256 + kw);
#pragma unroll
      for (int nt = 0; nt < 4; ++nt) {
        half8_t bv = *(const half8_t*)&X[nt * 16 + ml][ko];
        accF[0][nt] = mfma16(aF0, bv, accF[0][nt]);
        accF[1][nt] = mfma16(aF1, bv, accF[1][nt]);
        accG[0][nt] = mfma16(aG0, bv, accG[0][nt]);
        accG[1][nt] = mfma16(aG1, bv, accG[1][nt]);
      }
    }
  }

  // ---- gate in registers ----
  half4_t og[2][4];
#pragma unroll
  for (int mt = 0; mt < 2; ++mt) {
    const int mb = 32 * w + mt * 16 + mq * 4;
    floatx4 bfv = *(const floatx4*)(bfl + mb);
    floatx4 bgv = *(const floatx4*)(bgl + mb);
#pragma unroll
    for (int nt = 0; nt < 4; ++nt) {
#pragma unroll
      for (int r = 0; r < 4; ++r) {
        float fv = fast_tanh(accF[mt][nt][r] + bfv[r]);
        float gv = fast_sigmoid(accG[mt][nt][r] + bgv[r]);
        og[mt][nt][r] = (_Float16)(fv * gv);
      }
    }
  }
  __syncthreads();  // b2: all Xs0 reads complete -> reuse as Os

  _Float16(*Os)[136] = Xs0;
#pragma unroll
  for (int mt = 0; mt < 2; ++mt) {
    const int mb = 32 * w + mt * 16 + mq * 4;
#pragma unroll
    for (int nt = 0; nt < 4; ++nt)
      *(half4_t*)&Os[nt * 16 + ml][mb] = og[mt][nt];
  }
  __syncthreads();  // b3: Os visible

  // ---- GEMM2: x = WR(128x128) @ out ----
  floatx4 accX[2][4];
#pragma unroll
  for (int a = 0; a < 2; ++a)
#pragma unroll
    for (int cc = 0; cc < 4; ++cc) accX[a][cc] = floatx4{0.f, 0.f, 0.f, 0.f};
  const _Float16* Ar = WRl + (size_t)(32 * w + ml) * 128;
#pragma unroll
  for (int kk = 0; kk < 4; ++kk) {
    const int ko = kk * 32 + mq * 8;
    half8_t a0 = *(const half8_t*)(Ar + ko);
    half8_t a1 = *(const half8_t*)(Ar + 16 * 128 + ko);
#pragma unroll
    for (int nt = 0; nt < 4; ++nt) {
      half8_t bv = *(const half8_t*)&Os[nt * 16 + ml][ko];
      accX[0][nt] = mfma16(a0, bv, accX[0][nt]);
      accX[1][nt] = mfma16(a1, bv, accX[1][nt]);
    }
  }

  // ---- register epilogue: R_new = x + br + R_old (from Xs1) ----
  half4_t xo[2][4];
#pragma unroll
  for (int mt = 0; mt < 2; ++mt) {
    const int mb = 32 * w + mt * 16 + mq * 4;
    floatx4 brv = *(const floatx4*)(brl + mb);
#pragma unroll
    for (int nt = 0; nt < 4; ++nt) {
      const int n = nt * 16 + ml;
      half4_t rold = *(const half4_t*)&Xs1[n][mb];
#pragma unroll
      for (int r = 0; r < 4; ++r)
        xo[mt][nt][r] = (_Float16)(accX[mt][nt][r] + brv[r] + (float)rold[r]);
    }
  }
  __syncthreads();  // b4: all Os + Xs1 reads complete

#pragma unroll
  for (int mt = 0; mt < 2; ++mt) {
    const int mb = 32 * w + mt * 16 + mq * 4;
#pragma unroll
    for (int nt = 0; nt < 4; ++nt)
      *(half4_t*)&Os[nt * 16 + ml][mb] = xo[mt][nt];
  }
  __syncthreads();  // b5

  // ---- coalesced store: 16B/lane, row-contiguous (plain: stays in L2) ----
#pragma unroll
  for (int it = 0; it < 4; ++it) {
    int i = it * 256 + tid;
    int n = i >> 4, cc = i & 15;
    *(half8_t*)(Ro + (size_t)(u0 + n) * HIDC + cc * 8) = *(const half8_t*)&Os[n][cc * 8];
  }
  __syncthreads();  // smem dead before caller reuses it
}

// ---------------- phase 21: head for one tile --------------------------------
__device__ __forceinline__ void phase_head(
    const _Float16* __restrict__ Ra, const _Float16* __restrict__ Rz,
    const _Float16* __restrict__ W1h, const _Float16* __restrict__ W2h,
    const float* __restrict__ b1, const float* __restrict__ b2,
    float* __restrict__ outb, int u0, char* smem) {
  _Float16* Hs = (_Float16*)smem;              // [64][136]
  _Float16* H1s = (_Float16*)(smem + 17408);   // [64][136]
  const int tid = threadIdx.x;
  const int lane = tid & 63;
  const int w = tid >> 6;
  const int ml = lane & 15;
  const int mq = lane >> 4;

  // stage relu(Rfin - R0): 8 sc0 loads (own-tile data; L1 bypass for safety)
  const int cc = tid & 15;
  const int nb = tid >> 4;  // n = it*16 + nb
  const _Float16* pa[4];
  const _Float16* pz[4];
#pragma unroll
  for (int it = 0; it < 4; ++it) {
    int u = u0 + it * 16 + nb;  // u0 <= 8128, nb <= 15 -> u < TT
    pa[it] = Ra + (size_t)u * HIDC + cc * 8;
    pz[it] = Rz + (size_t)u * HIDC + cc * 8;
  }
  floatx4 a0, a1, a2, a3, z0, z1, z2, z3;
  cload8(pa[0], pa[1], pa[2], pa[3], pz[0], pz[1], pz[2], pz[3],
         a0, a1, a2, a3, z0, z1, z2, z3);
  floatx4 aa[4] = {a0, a1, a2, a3};
  floatx4 zz[4] = {z0, z1, z2, z3};
#pragma unroll
  for (int it = 0; it < 4; ++it) {
    half8_t av = *(half8_t*)&aa[it];
    half8_t zv = *(half8_t*)&zz[it];
    half8_t h;
#pragma unroll
    for (int tq = 0; tq < 8; ++tq) {
      float v = (float)av[tq] - (float)zv[tq];
      h[tq] = (_Float16)(v > 0.f ? v : 0.f);
    }
    *(half8_t*)&Hs[(it * 16 + nb) * 136 + cc * 8] = h;
  }
  __syncthreads();

  floatx4 accO[4][4];
#pragma unroll
  for (int a = 0; a < 4; ++a)
#pragma unroll
    for (int c = 0; c < 4; ++c) accO[a][c] = floatx4{0.f, 0.f, 0.f, 0.f};

  for (int p = 0; p < 4; ++p) {
    floatx4 acc1[2][4];
#pragma unroll
    for (int a = 0; a < 2; ++a)
#pragma unroll
      for (int c = 0; c < 4; ++c) acc1[a][c] = floatx4{0.f, 0.f, 0.f, 0.f};
    const _Float16* A1 = W1h + (size_t)(128 * p + 32 * w + ml) * 128;
#pragma unroll
    for (int kk = 0; kk < 4; ++kk) {
      const int ko = kk * 32 + mq * 8;
      half8_t av0 = *(const half8_t*)(A1 + ko);
      half8_t av1 = *(const half8_t*)(A1 + 16 * 128 + ko);
#pragma unroll
      for (int nt = 0; nt < 4; ++nt) {
        half8_t bv = *(const half8_t*)&Hs[(nt * 16 + ml) * 136 + ko];
        acc1[0][nt] = mfma16(av0, bv, acc1[0][nt]);
        acc1[1][nt] = mfma16(av1, bv, acc1[1][nt]);
      }
    }
    __syncthreads();
#pragma unroll
    for (int mt = 0; mt < 2; ++mt) {
      const int kc = 32 * w + mt * 16 + mq * 4;
      floatx4 bv = *(const floatx4*)(b1 + 128 * p + kc);
#pragma unroll
      for (int nt = 0; nt < 4; ++nt) {
        half4_t h;
#pragma unroll
        for (int r = 0; r < 4; ++r) {
          float v = acc1[mt][nt][r] + bv[r];
          h[r] = (_Float16)(v > 0.f ? v : 0.f);
        }
        *(half4_t*)&H1s[(nt * 16 + ml) * 136 + kc] = h;
      }
    }
    __syncthreads();
    const _Float16* A2 = W2h + (size_t)(64 * w + ml) * 512 + p * 128;
#pragma unroll
    for (int kk = 0; kk < 4; ++kk) {
      const int ko = kk * 32 + mq * 8;
#pragma unroll
      for (int nt = 0; nt < 4; ++nt) {
        half8_t bv = *(const half8_t*)&H1s[(nt * 16 + ml) * 136 + ko];
#pragma unroll
        for (int mt = 0; mt < 4; ++mt) {
          half8_t av = *(const half8_t*)(A2 + (size_t)(mt * 16) * 512 + ko);
          accO[mt][nt] = mfma16(av, bv, accO[mt][nt]);
        }
      }
    }
    __syncthreads();
  }

  _Float16* Ot = (_Float16*)smem;  // [64][264]
#pragma unroll
  for (int mt = 0; mt < 4; ++mt) {
    const int m = 64 * w + mt * 16 + mq * 4;
    floatx4 bv = *(const floatx4*)(b2 + m);
#pragma unroll
    for (int nt = 0; nt < 4; ++nt) {
      const int n = nt * 16 + ml;
      half4_t h;
#pragma unroll
      for (int r = 0; r < 4; ++r) h[r] = (_Float16)(accO[mt][nt][r] + bv[r]);
      *(half4_t*)&Ot[n * 264 + m] = h;
    }
  }
  __syncthreads();
#pragma unroll
  for (int it = 0; it < 8; ++it) {
    int i = it * 256 + tid;
    int n = i >> 5;
    int g = i & 31;
    int u = u0 + n;
    if (u >= GOODC) {
      half8_t v = *(const half8_t*)&Ot[n * 264 + g * 8];
      float* dst = outb + (size_t)(u - GOODC) * 256 + g * 8;
      floatx4 v0, v1;
#pragma unroll
      for (int tq = 0; tq < 4; ++tq) { v0[tq] = (float)v[tq]; v1[tq] = (float)v[4 + tq]; }
      *(floatx4*)dst = v0;
      *(floatx4*)(dst + 4) = v1;
    }
  }
}

// ---------------- persistent dataflow kernel ---------------------------------
__global__ __launch_bounds__(256, 3) void mega_kernel(
    const float* __restrict__ inp, const _Float16* __restrict__ WIh,
    const float* __restrict__ bi, const _Float16* __restrict__ WFG,
    const _Float16* __restrict__ WRh, const float* __restrict__ bf,
    const float* __restrict__ bg, const float* __restrict__ br,
    const _Float16* __restrict__ W1h, const _Float16* __restrict__ W2h,
    const float* __restrict__ b1, const float* __restrict__ b2,
    _Float16* __restrict__ R0h, _Float16* __restrict__ Ph,
    _Float16* __restrict__ Qh, float* __restrict__ out) {
  __shared__ __align__(16) char smem[34816];
  __shared__ int s_t0, s_light;
  const int tid = threadIdx.x;

  // ---- startup: XCD self-assignment + BOUNDED rendezvous + mode decision ----
  if (tid == 0) {
    unsigned xcd;
    asm volatile("s_getreg_b32 %0, hwreg(HW_REG_XCC_ID)" : "=s"(xcd));
    xcd &= 7;
    int slot = __hip_atomic_fetch_add(&g_qhead[xcd], 1, __ATOMIC_RELAXED,
                                      __HIP_MEMORY_SCOPE_AGENT);
    __hip_atomic_fetch_add(&g_arrive, 1, __ATOMIC_RELEASE,
                           __HIP_MEMORY_SCOPE_AGENT);
    int ok = 1, it = 0;
    while (__hip_atomic_load(&g_arrive, __ATOMIC_ACQUIRE,
                             __HIP_MEMORY_SCOPE_AGENT) < NBLK) {
      if (++it > RDV_CAP) {  // blocks not co-resident: degrade, don't hang
        ok = 0;
        __hip_atomic_store(&g_broken, 1, __ATOMIC_RELAXED,
                           __HIP_MEMORY_SCOPE_AGENT);
        break;
      }
      __builtin_amdgcn_s_sleep(8);
    }
    int light = ok;
    if (ok) {
#pragma unroll
      for (int x = 0; x < 8; ++x)
        light &= (__hip_atomic_load(&g_qhead[x], __ATOMIC_RELAXED,
                                    __HIP_MEMORY_SCOPE_AGENT) == NBLK / 8);
    }
    int bb, j0;
    if (light) { bb = (int)xcd; j0 = slot * 2; }        // batch pinned to XCD
    else       { bb = blockIdx.x >> 6; j0 = (blockIdx.x & 63) * 2; }
    s_t0 = bb * 128 + j0;
    s_light = light;
  }
  __syncthreads();
  const int t0 = s_t0;
  const int light = s_light;
  const int bb = t0 >> 7;
  const int j0 = t0 & 127;

#pragma unroll 1
  for (int q = 0; q < NPHASE; ++q) {
#pragma unroll 1
    for (int tt = 0; tt < 2; ++tt) {
      const int j = j0 + tt;
      const int u0 = j * 64;

      // ---- dependency gate (parallel bounded flag spins) ----
      if (q >= 1 && q <= 20) {
        const int dd = 1 << ((q - 1) % 10);
        int jlo = j - ((dd + 63) >> 6);          // RAW: producers behind
        int jhi = j;
        if (q >= 3)                              // WAR: ping-pong buffer reuse
          jhi = j + (((1 << ((q - 2) % 10)) + 63) >> 6);
        if (jlo < 0) jlo = 0;
        if (jhi > 127) jhi = 127;
        const int cnt = jhi - jlo + 1;           // <= 19: single wave spins
        if (tid < cnt) {
          const int jj = jlo + tid;
          if ((jj >> 1) != (j0 >> 1)) {          // own pair satisfied by order
            int* f = &g_progress[(bb << 7) + jj];
            int it = 0;
            while (__hip_atomic_load(f, __ATOMIC_RELAXED,
                                     __HIP_MEMORY_SCOPE_AGENT) < q) {
              if (!(++it & 15) &&
                  __hip_atomic_load(&g_broken, __ATOMIC_RELAXED,
                                    __HIP_MEMORY_SCOPE_AGENT))
                break;
              if (it > GATE_CAP) {               // protocol wedged: degrade
                __hip_atomic_store(&g_broken, 1, __ATOMIC_RELAXED,
                                   __HIP_MEMORY_SCOPE_AGENT);
                break;
              }
              __builtin_amdgcn_s_sleep(2);
            }
          }
        }
        __syncthreads();
        if (!light) __builtin_amdgcn_fence(__ATOMIC_ACQUIRE, "agent");
      }

      // ---- phase body (r7-verified bodies, sc0 staging) ----
      if (q == 0) {
        phase_input(inp + (size_t)bb * 256 * TT, WIh, bi,
                    R0h + (size_t)bb * TT * HIDC, u0, smem);
      } else if (q <= 20) {
        const int l = q - 1;
        const int d = 1 << (l % 10);
        const _Float16* rin = (q == 1) ? R0h : ((q & 1) ? Qh : Ph);
        _Float16* rout = (q & 1) ? Ph : Qh;
        phase_layer(rin + (size_t)bb * TT * HIDC,
                    rout + (size_t)bb * TT * HIDC,
                    WFG + (size_t)l * 65536, WRh + (size_t)l * 16384,
                    bf + l * 128, bg + l * 128, br + l * 128, d, u0, smem);
      } else if (j >= 31) {  // head: only tiles overlapping [GOODC, TT)
        phase_head(Qh + (size_t)bb * TT * HIDC, R0h + (size_t)bb * TT * HIDC,
                   W1h, W2h, b1, b2, out + (size_t)bb * TGT * 256, u0, smem);
      }

      // ---- completion / release ----
      if (q <= 20) {
        if (light) {
          asm volatile("s_waitcnt vmcnt(0)" ::: "memory");  // stores in L2
        } else {
          __builtin_amdgcn_fence(__ATOMIC_RELEASE, "agent"); // wb to LLC
        }
        __syncthreads();
        if (tid == 0)
          __hip_atomic_store(&g_progress[(bb << 7) + j], q + 1,
                             __ATOMIC_RELAXED, __HIP_MEMORY_SCOPE_AGENT);
      } else {
        __syncthreads();  // protect smem before own next tile
      }
    }
  }
}

extern "C" void kernel_launch(void* const* d_in, const int* in_sizes, int n_in,
                              void* d_out, int out_size, void* d_ws, size_t ws_size,
                              hipStream_t stream) {
  const float* inputs = (const float*)d_in[0];
  const float* Wi = (const float*)d_in[1];
  const float* bi = (const float*)d_in[2];
  const float* Wf = (const float*)d_in[3];
  const float* bf = (const float*)d_in[4];
  const float* Wg = (const float*)d_in[5];
  const float* bg = (const float*)d_in[6];
  const float* Wr = (const float*)d_in[7];
  const float* br = (const float*)d_in[8];
  const float* W1 = (const float*)d_in[9];
  const float* b1 = (const float*)d_in[10];
  const float* W2 = (const float*)d_in[11];
  const float* b2 = (const float*)d_in[12];
  float* out = (float*)d_out;

  // workspace layout (~54 MB): three fp16 res buffers + fp16 weights
  char* ws = (char*)d_ws;
  _Float16* R0h = (_Float16*)(ws + 0);
  _Float16* Ph  = (_Float16*)(ws + 16777216);
  _Float16* Qh  = (_Float16*)(ws + 33554432);
  _Float16* WFG = (_Float16*)(ws + 50331648);
  _Float16* WRh = (_Float16*)(ws + 52953088);
  _Float16* WIh = (_Float16*)(ws + 53608448);
  _Float16* W1h = (_Float16*)(ws + 53673984);
  _Float16* W2h = (_Float16*)(ws + 53805056);

  prep_kernel<<<dim3(512), dim3(256), 0, stream>>>(Wi, Wf, Wg, Wr, W1, W2,
                                                   WIh, WFG, WRh, W1h, W2h);
  mega_kernel<<<dim3(NBLK), dim3(256), 0, stream>>>(
      inputs, WIh, bi, WFG, WRh, bf, bg, br, W1h, W2h, b1, b2,
      R0h, Ph, Qh, out);
}

// Round 5
// 904.732 us; speedup vs baseline: 3.7098x; 1.2669x over previous
//
#include <hip/hip_runtime.h>

// WaveNet on gfx950, fp16 MFMA path, round 10.
// r9 (dataflow + XCD affinity) PASSED but 1146us: FETCH+WRITE = 2.29 GB at
// 2.1 TB/s == kernel duration -> LLC-traffic-bound. Res staging (48 KB/tile/
// phase) has reuse distance > 4MB L2 -> every publish evicted before use.
// r10: LDS-resident residual. Each block keeps its tile's R (and R0) in LDS
// across all 22 phases: tap1 never touches global; tap0 reads only the
// neighbor-owned prefix (d rows if d<64, else one predecessor tile);
// publishes shrink to ext=min(2^(q%10),64) rows. Global res traffic drops
// ~6x and becomes L2-resident. Blocks run tile s then tile 64+s (2 chunks);
// cross-chunk tails go to a dedicated ST buffer (in the old R0h slot; R0
// publish is 1 row/tile, head reads R0 from LDS) so chunk-0 tails are never
// WAR-blocked by chunk-1. Gates tighten to 2 flags: RAW producer jraw,
// WAR reader jwar. Protocol otherwise r9 (proven): XCD-affine light mode,
// sc0 staging loads, plain stores + vmcnt(0) release, LLC-resolved relaxed
// flags, bounded spins + g_broken, heavy fallback with agent fences.
// LDS 52224 B -> 3 blocks/CU capacity, need 2 (512 blocks).

#define TT 8192
#define HIDC 128
#define GOODC 2046
#define TGT 6146
#define NL 20
#define NTILES 1024
#define NBLK 512
#define GATE_CAP (1 << 18)
#define RDV_CAP (1 << 16)
#define STROWS 2046
#define STOFF(x) (((1 << ((x) % 10)) - 1) + 1023 * ((x) / 10))

typedef _Float16 half8_t __attribute__((ext_vector_type(8)));
typedef _Float16 half4_t __attribute__((ext_vector_type(4)));
typedef float floatx4 __attribute__((ext_vector_type(4)));

__device__ int g_progress[NTILES];
__device__ int g_qhead[8];
__device__ int g_arrive;
__device__ int g_broken;

__device__ __forceinline__ floatx4 mfma16(half8_t a, half8_t b, floatx4 c) {
  return __builtin_amdgcn_mfma_f32_16x16x32_f16(a, b, c, 0, 0, 0);
}
__device__ __forceinline__ float fast_sigmoid(float x) {
  return __builtin_amdgcn_rcpf(1.0f + __expf(-x));
}
__device__ __forceinline__ float fast_tanh(float x) {
  return 2.0f * __builtin_amdgcn_rcpf(1.0f + __expf(-2.0f * x)) - 1.0f;
}

// 4 L1-bypass (sc0) 16B loads, one waitcnt (same-XCD L2 is coherence point).
__device__ __forceinline__ void cload4(const void* p0, const void* p1,
                                       const void* p2, const void* p3,
                                       floatx4& r0, floatx4& r1, floatx4& r2,
                                       floatx4& r3) {
  asm volatile(
      "global_load_dwordx4 %0, %4, off sc0\n\t"
      "global_load_dwordx4 %1, %5, off sc0\n\t"
      "global_load_dwordx4 %2, %6, off sc0\n\t"
      "global_load_dwordx4 %3, %7, off sc0\n\t"
      "s_waitcnt vmcnt(0)"
      : "=&v"(r0), "=&v"(r1), "=&v"(r2), "=&v"(r3)
      : "v"(p0), "v"(p1), "v"(p2), "v"(p3)
      : "memory");
}

__device__ __forceinline__ void spin_tile(int idx, int q) {
  int* f = &g_progress[idx];
  int it = 0;
  while (__hip_atomic_load(f, __ATOMIC_RELAXED, __HIP_MEMORY_SCOPE_AGENT) < q) {
    if (!(++it & 15) && __hip_atomic_load(&g_broken, __ATOMIC_RELAXED,
                                          __HIP_MEMORY_SCOPE_AGENT))
      break;
    if (it > GATE_CAP) {
      __hip_atomic_store(&g_broken, 1, __ATOMIC_RELAXED,
                         __HIP_MEMORY_SCOPE_AGENT);
      break;
    }
    __builtin_amdgcn_s_sleep(2);
  }
}

// ---------------- weight prep + flag reset ----------------
__global__ void prep_kernel(const float* __restrict__ Wi, const float* __restrict__ Wf,
                            const float* __restrict__ Wg, const float* __restrict__ Wr,
                            const float* __restrict__ W1, const float* __restrict__ W2,
                            _Float16* __restrict__ WIh, _Float16* __restrict__ WFG,
                            _Float16* __restrict__ WRh, _Float16* __restrict__ W1h,
                            _Float16* __restrict__ W2h) {
  int idx = blockIdx.x * blockDim.x + threadIdx.x;
  int stride = gridDim.x * blockDim.x;
  for (int i = idx; i < NTILES; i += stride) g_progress[i] = 0;
  for (int i = idx; i < 8; i += stride) g_qhead[i] = 0;
  if (idx == 0) { g_arrive = 0; g_broken = 0; }
  for (int i = idx; i < NL * 256 * 256; i += stride) {
    int l = i >> 16; int m = (i >> 8) & 255; int k = i & 255;
    int tap = k >> 7; int ci = k & 127;
    float v;
    if (m < 128) v = Wf[(((size_t)l * 128 + m) * 128 + ci) * 2 + tap];
    else         v = Wg[(((size_t)l * 128 + (m - 128)) * 128 + ci) * 2 + tap];
    WFG[i] = (_Float16)v;
  }
  for (int i = idx; i < NL * 128 * 128; i += stride) WRh[i] = (_Float16)Wr[i];
  for (int i = idx; i < 128 * 256; i += stride) WIh[i] = (_Float16)Wi[i];
  for (int i = idx; i < 512 * 128; i += stride) W1h[i] = (_Float16)W1[i];
  for (int i = idx; i < 256 * 512; i += stride) W2h[i] = (_Float16)W2[i];
}

// ---------------- phase 0: input conv -> Rown/R0own (LDS) + 1-row publish ----
__device__ __forceinline__ void phase_input(
    const float* __restrict__ ib, const _Float16* __restrict__ WIh,
    const float* __restrict__ bi, _Float16* __restrict__ pbout,
    _Float16* __restrict__ stout, int u0, int j, char* smem) {
  _Float16(*Rown)[136] = (_Float16(*)[136])smem;
  _Float16(*R0own)[136] = (_Float16(*)[136])(smem + 17408);
  _Float16(*Xs)[264] = (_Float16(*)[264])(smem + 17408);  // scratch S1+S2
  const int tid = threadIdx.x;
  const int lane = tid & 63;
  const int w = tid >> 6;
  const int ml = lane & 15;
  const int mq = lane >> 4;

#pragma unroll
  for (int it = 0; it < 4; ++it) {
    int i = it * 256 + tid;
    int n4 = i & 15;
    int kg = i >> 4;
    const float* src = ib + (size_t)(kg * 4) * TT + u0 + n4 * 4;
    floatx4 c0 = *(const floatx4*)(src);
    floatx4 c1 = *(const floatx4*)(src + TT);
    floatx4 c2 = *(const floatx4*)(src + 2 * TT);
    floatx4 c3 = *(const floatx4*)(src + 3 * TT);
#pragma unroll
    for (int tq = 0; tq < 4; ++tq) {
      half4_t h;
      h[0] = (_Float16)c0[tq]; h[1] = (_Float16)c1[tq];
      h[2] = (_Float16)c2[tq]; h[3] = (_Float16)c3[tq];
      *(half4_t*)&Xs[n4 * 4 + tq][kg * 4] = h;
    }
  }
  __syncthreads();

  floatx4 acc[2][4];
#pragma unroll
  for (int a = 0; a < 2; ++a)
#pragma unroll
    for (int c = 0; c < 4; ++c) acc[a][c] = floatx4{0.f, 0.f, 0.f, 0.f};
  const _Float16* Aw = WIh + (size_t)(32 * w + ml) * 256;
#pragma unroll
  for (int kk = 0; kk < 8; ++kk) {
    const int ko = kk * 32 + mq * 8;
    half8_t a0 = *(const half8_t*)(Aw + ko);
    half8_t a1 = *(const half8_t*)(Aw + 16 * 256 + ko);
#pragma unroll
    for (int nt = 0; nt < 4; ++nt) {
      half8_t bv = *(const half8_t*)&Xs[nt * 16 + ml][ko];
      acc[0][nt] = mfma16(a0, bv, acc[0][nt]);
      acc[1][nt] = mfma16(a1, bv, acc[1][nt]);
    }
  }
  __syncthreads();
  float* Xf = (float*)(smem + 17408);
#pragma unroll
  for (int mt = 0; mt < 2; ++mt) {
    const int mb = 32 * w + mt * 16 + mq * 4;
#pragma unroll
    for (int nt = 0; nt < 4; ++nt)
      *(floatx4*)&Xf[(nt * 16 + ml) * 132 + mb] = acc[mt][nt];
  }
  __syncthreads();
  half8_t hv[4];
#pragma unroll
  for (int it = 0; it < 4; ++it) {
    int i = it * 256 + tid;
    int n = i >> 4; int cq = i & 15;
    floatx4 x0 = *(const floatx4*)&Xf[n * 132 + cq * 8];
    floatx4 x1 = *(const floatx4*)&Xf[n * 132 + cq * 8 + 4];
    floatx4 b0 = *(const floatx4*)(bi + cq * 8);
    floatx4 b1v = *(const floatx4*)(bi + cq * 8 + 4);
#pragma unroll
    for (int tq = 0; tq < 4; ++tq) {
      hv[it][tq] = (_Float16)(x0[tq] + b0[tq]);
      hv[it][4 + tq] = (_Float16)(x1[tq] + b1v[tq]);
    }
  }
  __syncthreads();  // Xf reads done; S1+S2 scratch dead
#pragma unroll
  for (int it = 0; it < 4; ++it) {
    int i = it * 256 + tid;
    int n = i >> 4; int cq = i & 15;
    *(half8_t*)&Rown[n][cq * 8] = hv[it];
    *(half8_t*)&R0own[n][cq * 8] = hv[it];
    if (n == 63) {  // publish ext(res_0)=1 row
      *(half8_t*)(pbout + (size_t)(u0 + 63) * HIDC + cq * 8) = hv[it];
      if (j == 63)  // ST[0] row 0 (position 4095)
        *(half8_t*)(stout + cq * 8) = hv[it];
    }
  }
}

// ---------------- phases 1..20: one layer; R stays in LDS ----------------
__device__ __forceinline__ void phase_layer(
    const _Float16* __restrict__ pbin, _Float16* __restrict__ pbout,
    const _Float16* __restrict__ stin, _Float16* __restrict__ stout,
    const _Float16* __restrict__ WFGl, const _Float16* __restrict__ WRl,
    const float* __restrict__ bfl, const float* __restrict__ bgl,
    const float* __restrict__ brl, int d, int u0, int ext, int nst,
    bool use_st, char* smem) {
  _Float16(*Rown)[136] = (_Float16(*)[136])smem;            // persistent R
  _Float16(*Xs0)[136] = (_Float16(*)[136])(smem + 34816);   // tap0 prefix; Os
  const int tid = threadIdx.x;
  const int lane = tid & 63;
  const int w = tid >> 6;
  const int ml = lane & 15;
  const int mq = lane >> 4;

  // ---- stage tap0 prefix: dd rows (dd = min(d,64)), sc0 loads ----
  const int dd = d < 64 ? d : 64;
  const int nch = dd << 4;
  {
    const void* sp[4];
    floatx4 rr[4];
#pragma unroll
    for (int k = 0; k < 4; ++k) {
      int i = tid + (k << 8);
      int row = i >> 4, cc = i & 15;
      const _Float16* src;
      if (use_st) {
        src = stin + (size_t)(u0 - 4096 + row) * HIDC + cc * 8;
      } else {
        int p = u0 - d + row;
        if (p < 0) p = 0;  // j=0 garbage, never consumed in valid region
        src = pbin + (size_t)p * HIDC + cc * 8;
      }
      sp[k] = (i < nch) ? (const void*)src
                        : (use_st ? (const void*)stin : (const void*)pbin);
    }
    cload4(sp[0], sp[1], sp[2], sp[3], rr[0], rr[1], rr[2], rr[3]);
#pragma unroll
    for (int k = 0; k < 4; ++k) {
      int i = tid + (k << 8);
      if (i < nch) {
        int row = i >> 4, cc = i & 15;
        *(floatx4*)&Xs0[row][cc * 8] = rr[k];
      }
    }
  }
  __syncthreads();  // b1

  // ---- B-row pointers: tap0 = prefix(Xs0) | own(Rown, shifted); tap1 = Rown
  const _Float16* brow0[4];
  const _Float16* brow1[4];
#pragma unroll
  for (int nt = 0; nt < 4; ++nt) {
    int n = nt * 16 + ml;
    brow1[nt] = &Rown[n][0];
    brow0[nt] = (n < dd) ? &Xs0[n][0] : &Rown[n - d][0];
  }

  // ---- GEMM1: [f;g](256 rows) x K=256 ----
  floatx4 accF[2][4], accG[2][4];
#pragma unroll
  for (int a = 0; a < 2; ++a)
#pragma unroll
    for (int cc = 0; cc < 4; ++cc) {
      accF[a][cc] = floatx4{0.f, 0.f, 0.f, 0.f};
      accG[a][cc] = floatx4{0.f, 0.f, 0.f, 0.f};
    }
  const _Float16* Af = WFGl + (size_t)(32 * w + ml) * 256;
  const _Float16* Ag = Af + 128 * 256;
#pragma unroll
  for (int h = 0; h < 2; ++h) {
#pragma unroll
    for (int kk = 0; kk < 4; ++kk) {
      const int ko = kk * 32 + mq * 8;
      const int kw = h * 128 + ko;
      half8_t aF0 = *(const half8_t*)(Af + kw);
      half8_t aF1 = *(const half8_t*)(Af + 16 * 256 + kw);
      half8_t aG0 = *(const half8_t*)(Ag + kw);
      half8_t aG1 = *(const half8_t*)(Ag + 16 * 256 + kw);
#pragma unroll
      for (int nt = 0; nt < 4; ++nt) {
        half8_t bv = *(const half8_t*)((h ? brow1[nt] : brow0[nt]) + ko);
        accF[0][nt] = mfma16(aF0, bv, accF[0][nt]);
        accF[1][nt] = mfma16(aF1, bv, accF[1][nt]);
        accG[0][nt] = mfma16(aG0, bv, accG[0][nt]);
        accG[1][nt] = mfma16(aG1, bv, accG[1][nt]);
      }
    }
  }

  // ---- gate in registers ----
  half4_t og[2][4];
#pragma unroll
  for (int mt = 0; mt < 2; ++mt) {
    const int mb = 32 * w + mt * 16 + mq * 4;
    floatx4 bfv = *(const floatx4*)(bfl + mb);
    floatx4 bgv = *(const floatx4*)(bgl + mb);
#pragma unroll
    for (int nt = 0; nt < 4; ++nt) {
#pragma unroll
      for (int r = 0; r < 4; ++r) {
        float fv = fast_tanh(accF[mt][nt][r] + bfv[r]);
        float gv = fast_sigmoid(accG[mt][nt][r] + bgv[r]);
        og[mt][nt][r] = (_Float16)(fv * gv);
      }
    }
  }
  __syncthreads();  // b2: Xs0 tap reads done -> reuse as Os

  _Float16(*Os)[136] = Xs0;
#pragma unroll
  for (int mt = 0; mt < 2; ++mt) {
    const int mb = 32 * w + mt * 16 + mq * 4;
#pragma unroll
    for (int nt = 0; nt < 4; ++nt)
      *(half4_t*)&Os[nt * 16 + ml][mb] = og[mt][nt];
  }
  __syncthreads();  // b3

  // ---- GEMM2: x = WR @ out ----
  floatx4 accX[2][4];
#pragma unroll
  for (int a = 0; a < 2; ++a)
#pragma unroll
    for (int cc = 0; cc < 4; ++cc) accX[a][cc] = floatx4{0.f, 0.f, 0.f, 0.f};
  const _Float16* Ar = WRl + (size_t)(32 * w + ml) * 128;
#pragma unroll
  for (int kk = 0; kk < 4; ++kk) {
    const int ko = kk * 32 + mq * 8;
    half8_t a0 = *(const half8_t*)(Ar + ko);
    half8_t a1 = *(const half8_t*)(Ar + 16 * 128 + ko);
#pragma unroll
    for (int nt = 0; nt < 4; ++nt) {
      half8_t bv = *(const half8_t*)&Os[nt * 16 + ml][ko];
      accX[0][nt] = mfma16(a0, bv, accX[0][nt]);
      accX[1][nt] = mfma16(a1, bv, accX[1][nt]);
    }
  }

  // ---- epilogue: R_new = x + br + R_old (Rown) ----
  half4_t xo[2][4];
#pragma unroll
  for (int mt = 0; mt < 2; ++mt) {
    const int mb = 32 * w + mt * 16 + mq * 4;
    floatx4 brv = *(const floatx4*)(brl + mb);
#pragma unroll
    for (int nt = 0; nt < 4; ++nt) {
      const int n = nt * 16 + ml;
      half4_t rold = *(const half4_t*)&Rown[n][mb];
#pragma unroll
      for (int r = 0; r < 4; ++r)
        xo[mt][nt][r] = (_Float16)(accX[mt][nt][r] + brv[r] + (float)rold[r]);
    }
  }
  __syncthreads();  // b4: all Rown/Os reads done

#pragma unroll
  for (int mt = 0; mt < 2; ++mt) {
    const int mb = 32 * w + mt * 16 + mq * 4;
#pragma unroll
    for (int nt = 0; nt < 4; ++nt)
      *(half4_t*)&Rown[nt * 16 + ml][mb] = xo[mt][nt];
  }
  __syncthreads();  // b5: Rown = res_q

  // ---- publish tail ext rows (+ST overlap), plain stores ----
  for (int i = tid; i < (ext << 4); i += 256) {
    int row = 64 - ext + (i >> 4);
    int cc = i & 15;
    half8_t v = *(const half8_t*)&Rown[row][cc * 8];
    int p = u0 + row;
    *(half8_t*)(pbout + (size_t)p * HIDC + cc * 8) = v;
    if (nst && p >= 4096 - nst)
      *(half8_t*)(stout + (size_t)(p - 4096 + nst) * HIDC + cc * 8) = v;
  }
}

// ---------------- phase 21: head (inputs all in LDS) ----------------
__device__ __forceinline__ void phase_head(
    const _Float16* __restrict__ W1h, const _Float16* __restrict__ W2h,
    const float* __restrict__ b1, const float* __restrict__ b2,
    float* __restrict__ outb, int u0, char* smem) {
  _Float16(*Rown)[136] = (_Float16(*)[136])smem;
  _Float16(*R0own)[136] = (_Float16(*)[136])(smem + 17408);
  _Float16* Hs = (_Float16*)(smem + 34816);   // [64][136] in S2
  _Float16* H1s = (_Float16*)(smem + 17408);  // reuses R0own after consume
  const int tid = threadIdx.x;
  const int lane = tid & 63;
  const int w = tid >> 6;
  const int ml = lane & 15;
  const int mq = lane >> 4;

  // Hs = relu(Rfin - R0), pure LDS
#pragma unroll
  for (int it = 0; it < 4; ++it) {
    int i = it * 256 + tid;
    int n = i >> 4; int cq = i & 15;
    half8_t a = *(const half8_t*)&Rown[n][cq * 8];
    half8_t z = *(const half8_t*)&R0own[n][cq * 8];
    half8_t h;
#pragma unroll
    for (int tq = 0; tq < 8; ++tq) {
      float v = (float)a[tq] - (float)z[tq];
      h[tq] = (_Float16)(v > 0.f ? v : 0.f);
    }
    *(half8_t*)&Hs[n * 136 + cq * 8] = h;
  }
  __syncthreads();  // R0own consumed -> H1s may reuse S1

  floatx4 accO[4][4];
#pragma unroll
  for (int a = 0; a < 4; ++a)
#pragma unroll
    for (int c = 0; c < 4; ++c) accO[a][c] = floatx4{0.f, 0.f, 0.f, 0.f};

  for (int p = 0; p < 4; ++p) {
    floatx4 acc1[2][4];
#pragma unroll
    for (int a = 0; a < 2; ++a)
#pragma unroll
      for (int c = 0; c < 4; ++c) acc1[a][c] = floatx4{0.f, 0.f, 0.f, 0.f};
    const _Float16* A1 = W1h + (size_t)(128 * p + 32 * w + ml) * 128;
#pragma unroll
    for (int kk = 0; kk < 4; ++kk) {
      const int ko = kk * 32 + mq * 8;
      half8_t av0 = *(const half8_t*)(A1 + ko);
      half8_t av1 = *(const half8_t*)(A1 + 16 * 128 + ko);
#pragma unroll
      for (int nt = 0; nt < 4; ++nt) {
        half8_t bv = *(const half8_t*)&Hs[(nt * 16 + ml) * 136 + ko];
        acc1[0][nt] = mfma16(av0, bv, acc1[0][nt]);
        acc1[1][nt] = mfma16(av1, bv, acc1[1][nt]);
      }
    }
    __syncthreads();
#pragma unroll
    for (int mt = 0; mt < 2; ++mt) {
      const int kc = 32 * w + mt * 16 + mq * 4;
      floatx4 bv = *(const floatx4*)(b1 + 128 * p + kc);
#pragma unroll
      for (int nt = 0; nt < 4; ++nt) {
        half4_t h;
#pragma unroll
        for (int r = 0; r < 4; ++r) {
          float v = acc1[mt][nt][r] + bv[r];
          h[r] = (_Float16)(v > 0.f ? v : 0.f);
        }
        *(half4_t*)&H1s[(nt * 16 + ml) * 136 + kc] = h;
      }
    }
    __syncthreads();
    const _Float16* A2 = W2h + (size_t)(64 * w + ml) * 512 + p * 128;
#pragma unroll
    for (int kk = 0; kk < 4; ++kk) {
      const int ko = kk * 32 + mq * 8;
#pragma unroll
      for (int nt = 0; nt < 4; ++nt) {
        half8_t bv = *(const half8_t*)&H1s[(nt * 16 + ml) * 136 + ko];
#pragma unroll
        for (int mt = 0; mt < 4; ++mt) {
          half8_t av = *(const half8_t*)(A2 + (size_t)(mt * 16) * 512 + ko);
          accO[mt][nt] = mfma16(av, bv, accO[mt][nt]);
        }
      }
    }
    __syncthreads();
  }

  _Float16* Ot = (_Float16*)(smem + 17408);  // [64][264] over S1+S2
#pragma unroll
  for (int mt = 0; mt < 4; ++mt) {
    const int m = 64 * w + mt * 16 + mq * 4;
    floatx4 bv = *(const floatx4*)(b2 + m);
#pragma unroll
    for (int nt = 0; nt < 4; ++nt) {
      const int n = nt * 16 + ml;
      half4_t h;
#pragma unroll
      for (int r = 0; r < 4; ++r) h[r] = (_Float16)(accO[mt][nt][r] + bv[r]);
      *(half4_t*)&Ot[n * 264 + m] = h;
    }
  }
  __syncthreads();
#pragma unroll
  for (int it = 0; it < 8; ++it) {
    int i = it * 256 + tid;
    int n = i >> 5;
    int g = i & 31;
    int u = u0 + n;
    if (u >= GOODC) {
      half8_t v = *(const half8_t*)&Ot[n * 264 + g * 8];
      float* dst = outb + (size_t)(u - GOODC) * 256 + g * 8;
      floatx4 v0, v1;
#pragma unroll
      for (int tq = 0; tq < 4; ++tq) { v0[tq] = (float)v[tq]; v1[tq] = (float)v[4 + tq]; }
      *(floatx4*)dst = v0;
      *(floatx4*)(dst + 4) = v1;
    }
  }
}

// ---------------- persistent dataflow kernel ---------------------------------
__global__ __launch_bounds__(256, 2) void mega_kernel(
    const float* __restrict__ inp, const _Float16* __restrict__ WIh,
    const float* __restrict__ bi, const _Float16* __restrict__ WFG,
    const _Float16* __restrict__ WRh, const float* __restrict__ bf,
    const float* __restrict__ bg, const float* __restrict__ br,
    const _Float16* __restrict__ W1h, const _Float16* __restrict__ W2h,
    const float* __restrict__ b1, const float* __restrict__ b2,
    _Float16* __restrict__ ST, _Float16* __restrict__ Ph,
    _Float16* __restrict__ Qh, float* __restrict__ out) {
  __shared__ __align__(16) char smem[52224];
  __shared__ int s_slot, s_bb, s_light;
  const int tid = threadIdx.x;

  // ---- startup: XCD self-assignment + bounded rendezvous (r9) ----
  if (tid == 0) {
    unsigned xcd;
    asm volatile("s_getreg_b32 %0, hwreg(HW_REG_XCC_ID)" : "=s"(xcd));
    xcd &= 7;
    int slot = __hip_atomic_fetch_add(&g_qhead[xcd], 1, __ATOMIC_RELAXED,
                                      __HIP_MEMORY_SCOPE_AGENT);
    __hip_atomic_fetch_add(&g_arrive, 1, __ATOMIC_RELEASE,
                           __HIP_MEMORY_SCOPE_AGENT);
    int ok = 1, it = 0;
    while (__hip_atomic_load(&g_arrive, __ATOMIC_ACQUIRE,
                             __HIP_MEMORY_SCOPE_AGENT) < NBLK) {
      if (++it > RDV_CAP) {
        ok = 0;
        __hip_atomic_store(&g_broken, 1, __ATOMIC_RELAXED,
                           __HIP_MEMORY_SCOPE_AGENT);
        break;
      }
      __builtin_amdgcn_s_sleep(8);
    }
    int light = ok;
    if (ok) {
#pragma unroll
      for (int x = 0; x < 8; ++x)
        light &= (__hip_atomic_load(&g_qhead[x], __ATOMIC_RELAXED,
                                    __HIP_MEMORY_SCOPE_AGENT) == NBLK / 8);
    }
    if (light) { s_bb = (int)xcd; s_slot = slot; }
    else       { s_bb = blockIdx.x >> 6; s_slot = blockIdx.x & 63; }
    s_light = light;
  }
  __syncthreads();
  const int slot = s_slot;
  const int bb = s_bb;
  const int light = s_light;

  _Float16* STb = ST + (size_t)bb * STROWS * HIDC;
  _Float16* Phb = Ph + (size_t)bb * TT * HIDC;
  _Float16* Qhb = Qh + (size_t)bb * TT * HIDC;
  const float* ib = inp + (size_t)bb * 256 * TT;
  float* outb = out + (size_t)bb * TGT * 256;

#pragma unroll 1
  for (int tt = 0; tt < 2; ++tt) {
    const int j = slot + tt * 64;
    const int u0 = j * 64;
#pragma unroll 1
    for (int q = 0; q < 22; ++q) {
      // ---- gate: 1 RAW producer + <=1 WAR reader ----
      if (q >= 1 && q <= 20) {
        const int dcur = 1 << ((q - 1) % 10);
        const int jraw = j - ((dcur + 63) >> 6);
        int jwar = -1;
        if (q >= 2) {
          const int dp = 1 << ((q - 2) % 10);
          int cand = j + ((dp + 63) >> 6);
          const int hi = (j & 64) ? 127 : 63;  // chunk-local (ST decouples)
          if (cand <= hi) jwar = cand;
        }
        if (tid == 0 && jraw >= 0) spin_tile(bb * 128 + jraw, q);
        if (tid == 1 && jwar >= 0) spin_tile(bb * 128 + jwar, q);
        __syncthreads();
        if (!light) __builtin_amdgcn_fence(__ATOMIC_ACQUIRE, "agent");
      }

      // ---- phase body ----
      if (q == 0) {
        phase_input(ib, WIh, bi, Qhb, STb /*STOFF(0)=0*/, u0, j, smem);
      } else if (q <= 20) {
        const int l = q - 1;
        const int d = 1 << (l % 10);
        const _Float16* pbin = ((q - 1) & 1) ? Phb : Qhb;
        _Float16* pbout = (q & 1) ? Phb : Qhb;
        const _Float16* stin = STb + (size_t)STOFF(q - 1) * HIDC;
        _Float16* stout = STb + (size_t)STOFF(q <= 19 ? q : 0) * HIDC;
        const int ext = (q <= 19) ? ((1 << (q % 10)) < 64 ? (1 << (q % 10)) : 64) : 0;
        const int nst = (j < 64 && q <= 19) ? (1 << (q % 10)) : 0;
        const bool use_st = (j >= 64) && (u0 - d < 4096);
        phase_layer(pbin, pbout, stin, stout, WFG + (size_t)l * 65536,
                    WRh + (size_t)l * 16384, bf + l * 128, bg + l * 128,
                    br + l * 128, d, u0, ext, nst, use_st, smem);
      } else if (j >= 31) {
        phase_head(W1h, W2h, b1, b2, outb, u0, smem);
      }

      // ---- release ----
      if (q <= 20) {
        if (light) {
          asm volatile("s_waitcnt vmcnt(0)" ::: "memory");  // stores in L2
        } else {
          __builtin_amdgcn_fence(__ATOMIC_RELEASE, "agent");
        }
        __syncthreads();
        if (tid == 0)
          __hip_atomic_store(&g_progress[bb * 128 + j], q + 1,
                             __ATOMIC_RELAXED, __HIP_MEMORY_SCOPE_AGENT);
      } else {
        __syncthreads();  // smem safe before next tile
      }
    }
  }
}

extern "C" void kernel_launch(void* const* d_in, const int* in_sizes, int n_in,
                              void* d_out, int out_size, void* d_ws, size_t ws_size,
                              hipStream_t stream) {
  const float* inputs = (const float*)d_in[0];
  const float* Wi = (const float*)d_in[1];
  const float* bi = (const float*)d_in[2];
  const float* Wf = (const float*)d_in[3];
  const float* bf = (const float*)d_in[4];
  const float* Wg = (const float*)d_in[5];
  const float* bg = (const float*)d_in[6];
  const float* Wr = (const float*)d_in[7];
  const float* br = (const float*)d_in[8];
  const float* W1 = (const float*)d_in[9];
  const float* b1 = (const float*)d_in[10];
  const float* W2 = (const float*)d_in[11];
  const float* b2 = (const float*)d_in[12];
  float* out = (float*)d_out;

  // workspace (unchanged 54 MB footprint): ST in old R0h slot
  char* ws = (char*)d_ws;
  _Float16* ST  = (_Float16*)(ws + 0);          // 8 x 2046 x 128 fp16 = 4.2 MB
  _Float16* Ph  = (_Float16*)(ws + 16777216);
  _Float16* Qh  = (_Float16*)(ws + 33554432);
  _Float16* WFG = (_Float16*)(ws + 50331648);
  _Float16* WRh = (_Float16*)(ws + 52953088);
  _Float16* WIh = (_Float16*)(ws + 53608448);
  _Float16* W1h = (_Float16*)(ws + 53673984);
  _Float16* W2h = (_Float16*)(ws + 53805056);

  prep_kernel<<<dim3(512), dim3(256), 0, stream>>>(Wi, Wf, Wg, Wr, W1, W2,
                                                   WIh, WFG, WRh, W1h, W2h);
  mega_kernel<<<dim3(NBLK), dim3(256), 0, stream>>>(
      inputs, WIh, bi, WFG, WRh, bf, bg, br, W1h, W2h, b1, b2,
      ST, Ph, Qh, out);
}

// Round 7
// 834.744 us; speedup vs baseline: 4.0209x; 1.0838x over previous
//
#include <hip/hip_runtime.h>

// WaveNet on gfx950, fp16 MFMA path, round 12.
// r10 (64-pos tiles, LLC-atomic flags): PASSED 849us, ripple-latency-bound.
// r11 (128-pos tiles + NEW plain-store/sc0-poll flag): FAILED absmax 0.458.
//   Dependency graph re-audited clean; the only unproven element was the
//   plain-flag protocol. Lesson repeated: novel coherence primitives fail.
// r12 = r11 structure + r10's PROVEN flag protocol (agent-scope relaxed
//   atomics, LLC-resolved, for both store and poll). One variable isolated.
//   - 128-pos tiles, 1 tile/block, 512 blocks: ripple chain ~halved vs r10.
//   - R0 in global (plain stores, sc0 readback at head); LDS = R(34.8K) +
//     scratch(34.8K) = 69.6KB -> exactly 2 blocks/CU.
//   - data path: plain stores -> vmcnt(0) -> barrier -> LLC flag; consumer
//     spins LLC flag -> barrier -> sc0 (L1-bypass) loads from shared L2.
//   - bounded spins + sticky g_broken (hang-proof), heavy fallback fences.

#define TT 8192
#define HIDC 128
#define GOODC 2046
#define TGT 6146
#define NL 20
#define TILE 128
#define NTB 64
#define NTILES 512
#define NBLK 512
#define GATE_CAP (1 << 18)
#define RDV_CAP (1 << 16)

typedef _Float16 half8_t __attribute__((ext_vector_type(8)));
typedef _Float16 half4_t __attribute__((ext_vector_type(4)));
typedef float floatx4 __attribute__((ext_vector_type(4)));

__device__ int g_progress[NTILES];
__device__ int g_qhead[8];
__device__ int g_arrive;
__device__ int g_broken;

__device__ __forceinline__ floatx4 mfma16(half8_t a, half8_t b, floatx4 c) {
  return __builtin_amdgcn_mfma_f32_16x16x32_f16(a, b, c, 0, 0, 0);
}
__device__ __forceinline__ float fast_sigmoid(float x) {
  return __builtin_amdgcn_rcpf(1.0f + __expf(-x));
}
__device__ __forceinline__ float fast_tanh(float x) {
  return 2.0f * __builtin_amdgcn_rcpf(1.0f + __expf(-2.0f * x)) - 1.0f;
}

// 8 L1-bypass (sc0) 16B loads, one waitcnt (L2 is the light-mode coherence pt)
__device__ __forceinline__ void cload8(
    const void* p0, const void* p1, const void* p2, const void* p3,
    const void* p4, const void* p5, const void* p6, const void* p7,
    floatx4& r0, floatx4& r1, floatx4& r2, floatx4& r3,
    floatx4& r4, floatx4& r5, floatx4& r6, floatx4& r7) {
  asm volatile(
      "global_load_dwordx4 %0, %8, off sc0\n\t"
      "global_load_dwordx4 %1, %9, off sc0\n\t"
      "global_load_dwordx4 %2, %10, off sc0\n\t"
      "global_load_dwordx4 %3, %11, off sc0\n\t"
      "global_load_dwordx4 %4, %12, off sc0\n\t"
      "global_load_dwordx4 %5, %13, off sc0\n\t"
      "global_load_dwordx4 %6, %14, off sc0\n\t"
      "global_load_dwordx4 %7, %15, off sc0\n\t"
      "s_waitcnt vmcnt(0)"
      : "=&v"(r0), "=&v"(r1), "=&v"(r2), "=&v"(r3),
        "=&v"(r4), "=&v"(r5), "=&v"(r6), "=&v"(r7)
      : "v"(p0), "v"(p1), "v"(p2), "v"(p3),
        "v"(p4), "v"(p5), "v"(p6), "v"(p7)
      : "memory");
}
__device__ __forceinline__ void cload4(const void* p0, const void* p1,
                                       const void* p2, const void* p3,
                                       floatx4& r0, floatx4& r1, floatx4& r2,
                                       floatx4& r3) {
  asm volatile(
      "global_load_dwordx4 %0, %4, off sc0\n\t"
      "global_load_dwordx4 %1, %5, off sc0\n\t"
      "global_load_dwordx4 %2, %6, off sc0\n\t"
      "global_load_dwordx4 %3, %7, off sc0\n\t"
      "s_waitcnt vmcnt(0)"
      : "=&v"(r0), "=&v"(r1), "=&v"(r2), "=&v"(r3)
      : "v"(p0), "v"(p1), "v"(p2), "v"(p3)
      : "memory");
}

// r10-proven bounded spin: LLC-resolved relaxed agent atomic load
__device__ __forceinline__ void spin_tile(int idx, int q) {
  int* f = &g_progress[idx];
  int it = 0;
  while (__hip_atomic_load(f, __ATOMIC_RELAXED, __HIP_MEMORY_SCOPE_AGENT) < q) {
    if (!(++it & 15) && __hip_atomic_load(&g_broken, __ATOMIC_RELAXED,
                                          __HIP_MEMORY_SCOPE_AGENT))
      break;
    if (it > GATE_CAP) {
      __hip_atomic_store(&g_broken, 1, __ATOMIC_RELAXED,
                         __HIP_MEMORY_SCOPE_AGENT);
      break;
    }
    __builtin_amdgcn_s_sleep(1);
  }
}

// ---------------- weight prep + flag reset ----------------
__global__ void prep_kernel(const float* __restrict__ Wi, const float* __restrict__ Wf,
                            const float* __restrict__ Wg, const float* __restrict__ Wr,
                            const float* __restrict__ W1, const float* __restrict__ W2,
                            _Float16* __restrict__ WIh, _Float16* __restrict__ WFG,
                            _Float16* __restrict__ WRh, _Float16* __restrict__ W1h,
                            _Float16* __restrict__ W2h) {
  int idx = blockIdx.x * blockDim.x + threadIdx.x;
  int stride = gridDim.x * blockDim.x;
  for (int i = idx; i < NTILES; i += stride) g_progress[i] = 0;
  for (int i = idx; i < 8; i += stride) g_qhead[i] = 0;
  if (idx == 0) { g_arrive = 0; g_broken = 0; }
  for (int i = idx; i < NL * 256 * 256; i += stride) {
    int l = i >> 16; int m = (i >> 8) & 255; int k = i & 255;
    int tap = k >> 7; int ci = k & 127;
    float v;
    if (m < 128) v = Wf[(((size_t)l * 128 + m) * 128 + ci) * 2 + tap];
    else         v = Wg[(((size_t)l * 128 + (m - 128)) * 128 + ci) * 2 + tap];
    WFG[i] = (_Float16)v;
  }
  for (int i = idx; i < NL * 128 * 128; i += stride) WRh[i] = (_Float16)Wr[i];
  for (int i = idx; i < 128 * 256; i += stride) WIh[i] = (_Float16)Wi[i];
  for (int i = idx; i < 512 * 128; i += stride) W1h[i] = (_Float16)W1[i];
  for (int i = idx; i < 256 * 512; i += stride) W2h[i] = (_Float16)W2[i];
}

// ---------------- phase 0 (one 64-row half): input conv ----------------
__device__ __forceinline__ void input_half(
    const float* __restrict__ ib, const _Float16* __restrict__ WIh,
    const float* __restrict__ bi, _Float16* __restrict__ R0g,
    _Float16* __restrict__ pbout, int u0t, int h, char* smem) {
  _Float16(*Rown)[136] = (_Float16(*)[136])smem;
  _Float16(*Xs)[264] = (_Float16(*)[264])(smem + 34816);
  const int u0 = u0t + 64 * h;
  const int tid = threadIdx.x;
  const int lane = tid & 63;
  const int w = tid >> 6;
  const int ml = lane & 15;
  const int mq = lane >> 4;

#pragma unroll
  for (int it = 0; it < 4; ++it) {
    int i = it * 256 + tid;
    int n4 = i & 15;
    int kg = i >> 4;
    const float* src = ib + (size_t)(kg * 4) * TT + u0 + n4 * 4;
    floatx4 c0 = *(const floatx4*)(src);
    floatx4 c1 = *(const floatx4*)(src + TT);
    floatx4 c2 = *(const floatx4*)(src + 2 * TT);
    floatx4 c3 = *(const floatx4*)(src + 3 * TT);
#pragma unroll
    for (int tq = 0; tq < 4; ++tq) {
      half4_t hh;
      hh[0] = (_Float16)c0[tq]; hh[1] = (_Float16)c1[tq];
      hh[2] = (_Float16)c2[tq]; hh[3] = (_Float16)c3[tq];
      *(half4_t*)&Xs[n4 * 4 + tq][kg * 4] = hh;
    }
  }
  __syncthreads();

  floatx4 acc[2][4];
#pragma unroll
  for (int a = 0; a < 2; ++a)
#pragma unroll
    for (int c = 0; c < 4; ++c) acc[a][c] = floatx4{0.f, 0.f, 0.f, 0.f};
  const _Float16* Aw = WIh + (size_t)(32 * w + ml) * 256;
#pragma unroll
  for (int kk = 0; kk < 8; ++kk) {
    const int ko = kk * 32 + mq * 8;
    half8_t a0 = *(const half8_t*)(Aw + ko);
    half8_t a1 = *(const half8_t*)(Aw + 16 * 256 + ko);
#pragma unroll
    for (int nt = 0; nt < 4; ++nt) {
      half8_t bv = *(const half8_t*)&Xs[nt * 16 + ml][ko];
      acc[0][nt] = mfma16(a0, bv, acc[0][nt]);
      acc[1][nt] = mfma16(a1, bv, acc[1][nt]);
    }
  }
  __syncthreads();
  float* Xf = (float*)(smem + 34816);
#pragma unroll
  for (int mt = 0; mt < 2; ++mt) {
    const int mb = 32 * w + mt * 16 + mq * 4;
#pragma unroll
    for (int nt = 0; nt < 4; ++nt)
      *(floatx4*)&Xf[(nt * 16 + ml) * 132 + mb] = acc[mt][nt];
  }
  __syncthreads();
#pragma unroll
  for (int it = 0; it < 4; ++it) {
    int i = it * 256 + tid;
    int n = i >> 4; int cq = i & 15;
    floatx4 x0 = *(const floatx4*)&Xf[n * 132 + cq * 8];
    floatx4 x1 = *(const floatx4*)&Xf[n * 132 + cq * 8 + 4];
    floatx4 b0 = *(const floatx4*)(bi + cq * 8);
    floatx4 b1v = *(const floatx4*)(bi + cq * 8 + 4);
    half8_t hh;
#pragma unroll
    for (int tq = 0; tq < 4; ++tq) {
      hh[tq] = (_Float16)(x0[tq] + b0[tq]);
      hh[4 + tq] = (_Float16)(x1[tq] + b1v[tq]);
    }
    *(half8_t*)&Rown[64 * h + n][cq * 8] = hh;   // Rown disjoint from scratch
    *(half8_t*)(R0g + (size_t)(u0 + n) * HIDC + cq * 8) = hh;
    if (h == 1 && n == 63)  // publish ext(res_0)=1 row (tile row 127)
      *(half8_t*)(pbout + (size_t)(u0 + n) * HIDC + cq * 8) = hh;
  }
  __syncthreads();  // scratch dead before next half / next phase
}

// ---------------- phases 1..20: one layer, 128-row tile in LDS --------------
__device__ __forceinline__ void phase_layer(
    const _Float16* __restrict__ pbin, _Float16* __restrict__ pbout,
    const _Float16* __restrict__ WFGl, const _Float16* __restrict__ WRl,
    const float* __restrict__ bfl, const float* __restrict__ bgl,
    const float* __restrict__ brl, int d, int u0, int ext, char* smem) {
  _Float16(*Rown)[136] = (_Float16(*)[136])smem;            // persistent R
  _Float16(*Xs0)[136] = (_Float16(*)[136])(smem + 34816);   // tap0 prefix; Os
  const int tid = threadIdx.x;
  const int lane = tid & 63;
  const int w = tid >> 6;
  const int ml = lane & 15;
  const int mq = lane >> 4;

  // ---- stage tap0 prefix: dd = min(d,128) rows via sc0 loads ----
  const int dd = d < TILE ? d : TILE;
  const int nch = dd << 4;              // 16B chunks
  {
    const void* sp[8];
#pragma unroll
    for (int k = 0; k < 8; ++k) {
      int i = tid + (k << 8);
      int row = i >> 4, cc = i & 15;
      int p = u0 - d + row;
      if (p < 0) p = 0;                 // left-edge garbage never consumed
      sp[k] = (i < nch) ? (const void*)(pbin + (size_t)p * HIDC + cc * 8)
                        : (const void*)pbin;
    }
    floatx4 rr0, rr1, rr2, rr3, rr4, rr5, rr6, rr7;
    cload8(sp[0], sp[1], sp[2], sp[3], sp[4], sp[5], sp[6], sp[7],
           rr0, rr1, rr2, rr3, rr4, rr5, rr6, rr7);
    floatx4 rr[8] = {rr0, rr1, rr2, rr3, rr4, rr5, rr6, rr7};
#pragma unroll
    for (int k = 0; k < 8; ++k) {
      int i = tid + (k << 8);
      if (i < nch) *(floatx4*)&Xs0[i >> 4][(i & 15) * 8] = rr[k];
    }
  }
  __syncthreads();  // b1

  // ---- B-row pointers ----
  const _Float16* brow0[8];
  const _Float16* brow1[8];
#pragma unroll
  for (int nt = 0; nt < 8; ++nt) {
    int n = nt * 16 + ml;
    brow1[nt] = &Rown[n][0];
    brow0[nt] = (n < dd) ? &Xs0[n][0] : &Rown[n - d][0];
  }

  // ---- GEMM1: [f;g](256) x N=128 x K=256 ----
  floatx4 accF[2][8], accG[2][8];
#pragma unroll
  for (int a = 0; a < 2; ++a)
#pragma unroll
    for (int cc = 0; cc < 8; ++cc) {
      accF[a][cc] = floatx4{0.f, 0.f, 0.f, 0.f};
      accG[a][cc] = floatx4{0.f, 0.f, 0.f, 0.f};
    }
  const _Float16* Af = WFGl + (size_t)(32 * w + ml) * 256;
  const _Float16* Ag = Af + 128 * 256;
#pragma unroll
  for (int h = 0; h < 2; ++h) {
#pragma unroll
    for (int kk = 0; kk < 4; ++kk) {
      const int ko = kk * 32 + mq * 8;
      const int kw = h * 128 + ko;
      half8_t aF0 = *(const half8_t*)(Af + kw);
      half8_t aF1 = *(const half8_t*)(Af + 16 * 256 + kw);
      half8_t aG0 = *(const half8_t*)(Ag + kw);
      half8_t aG1 = *(const half8_t*)(Ag + 16 * 256 + kw);
#pragma unroll
      for (int nt = 0; nt < 8; ++nt) {
        half8_t bv = *(const half8_t*)((h ? brow1[nt] : brow0[nt]) + ko);
        accF[0][nt] = mfma16(aF0, bv, accF[0][nt]);
        accF[1][nt] = mfma16(aF1, bv, accF[1][nt]);
        accG[0][nt] = mfma16(aG0, bv, accG[0][nt]);
        accG[1][nt] = mfma16(aG1, bv, accG[1][nt]);
      }
    }
  }

  // ---- gate in registers ----
  half4_t og[2][8];
#pragma unroll
  for (int mt = 0; mt < 2; ++mt) {
    const int mb = 32 * w + mt * 16 + mq * 4;
    floatx4 bfv = *(const floatx4*)(bfl + mb);
    floatx4 bgv = *(const floatx4*)(bgl + mb);
#pragma unroll
    for (int nt = 0; nt < 8; ++nt) {
#pragma unroll
      for (int r = 0; r < 4; ++r) {
        float fv = fast_tanh(accF[mt][nt][r] + bfv[r]);
        float gv = fast_sigmoid(accG[mt][nt][r] + bgv[r]);
        og[mt][nt][r] = (_Float16)(fv * gv);
      }
    }
  }
  __syncthreads();  // b2: Xs0 tap reads done -> reuse as Os

  _Float16(*Os)[136] = Xs0;
#pragma unroll
  for (int mt = 0; mt < 2; ++mt) {
    const int mb = 32 * w + mt * 16 + mq * 4;
#pragma unroll
    for (int nt = 0; nt < 8; ++nt)
      *(half4_t*)&Os[nt * 16 + ml][mb] = og[mt][nt];
  }
  __syncthreads();  // b3

  // ---- GEMM2: x = WR(128x128) @ out ----
  floatx4 accX[2][8];
#pragma unroll
  for (int a = 0; a < 2; ++a)
#pragma unroll
    for (int cc = 0; cc < 8; ++cc) accX[a][cc] = floatx4{0.f, 0.f, 0.f, 0.f};
  const _Float16* Ar = WRl + (size_t)(32 * w + ml) * 128;
#pragma unroll
  for (int kk = 0; kk < 4; ++kk) {
    const int ko = kk * 32 + mq * 8;
    half8_t a0 = *(const half8_t*)(Ar + ko);
    half8_t a1 = *(const half8_t*)(Ar + 16 * 128 + ko);
#pragma unroll
    for (int nt = 0; nt < 8; ++nt) {
      half8_t bv = *(const half8_t*)&Os[nt * 16 + ml][ko];
      accX[0][nt] = mfma16(a0, bv, accX[0][nt]);
      accX[1][nt] = mfma16(a1, bv, accX[1][nt]);
    }
  }

  // ---- epilogue: R_new = x + br + R_old ----
  half4_t xo[2][8];
#pragma unroll
  for (int mt = 0; mt < 2; ++mt) {
    const int mb = 32 * w + mt * 16 + mq * 4;
    floatx4 brv = *(const floatx4*)(brl + mb);
#pragma unroll
    for (int nt = 0; nt < 8; ++nt) {
      const int n = nt * 16 + ml;
      half4_t rold = *(const half4_t*)&Rown[n][mb];
#pragma unroll
      for (int r = 0; r < 4; ++r)
        xo[mt][nt][r] = (_Float16)(accX[mt][nt][r] + brv[r] + (float)rold[r]);
    }
  }
  __syncthreads();  // b4: all Rown/Os reads done

#pragma unroll
  for (int mt = 0; mt < 2; ++mt) {
    const int mb = 32 * w + mt * 16 + mq * 4;
#pragma unroll
    for (int nt = 0; nt < 8; ++nt)
      *(half4_t*)&Rown[nt * 16 + ml][mb] = xo[mt][nt];
  }
  __syncthreads();  // b5: Rown = res_q

  // ---- publish tail ext rows, plain stores (stay in local L2) ----
  for (int i = tid; i < (ext << 4); i += 256) {
    int row = TILE - ext + (i >> 4);
    int cc = i & 15;
    *(half8_t*)(pbout + (size_t)(u0 + row) * HIDC + cc * 8) =
        *(const half8_t*)&Rown[row][cc * 8];
  }
}

// ---------------- phase 21 (one 64-row half): head ----------------
__device__ __forceinline__ void head_half(
    const _Float16* __restrict__ R0g, const _Float16* __restrict__ W1h,
    const _Float16* __restrict__ W2h, const float* __restrict__ b1,
    const float* __restrict__ b2, float* __restrict__ outb, int u0t, int h,
    char* smem) {
  _Float16(*Rown)[136] = (_Float16(*)[136])smem;
  _Float16* Hs = (_Float16*)(smem + 34816);            // [64][136]
  _Float16* H1s = (_Float16*)(smem + 34816 + 17408);   // [64][136]
  const int u0 = u0t + 64 * h;
  const int tid = threadIdx.x;
  const int lane = tid & 63;
  const int w = tid >> 6;
  const int ml = lane & 15;
  const int mq = lane >> 4;

  // Hs = relu(Rfin(LDS) - R0(global, sc0))
  {
    const void* sp[4];
#pragma unroll
    for (int it = 0; it < 4; ++it) {
      int i = it * 256 + tid;
      sp[it] = R0g + (size_t)(u0 + (i >> 4)) * HIDC + (i & 15) * 8;
    }
    floatx4 z0, z1, z2, z3;
    cload4(sp[0], sp[1], sp[2], sp[3], z0, z1, z2, z3);
    floatx4 zz[4] = {z0, z1, z2, z3};
#pragma unroll
    for (int it = 0; it < 4; ++it) {
      int i = it * 256 + tid;
      int n = i >> 4; int cq = i & 15;
      half8_t a = *(const half8_t*)&Rown[64 * h + n][cq * 8];
      half8_t zv = *(half8_t*)&zz[it];
      half8_t hh;
#pragma unroll
      for (int tq = 0; tq < 8; ++tq) {
        float v = (float)a[tq] - (float)zv[tq];
        hh[tq] = (_Float16)(v > 0.f ? v : 0.f);
      }
      *(half8_t*)&Hs[n * 136 + cq * 8] = hh;
    }
  }
  __syncthreads();

  floatx4 accO[4][4];
#pragma unroll
  for (int a = 0; a < 4; ++a)
#pragma unroll
    for (int c = 0; c < 4; ++c) accO[a][c] = floatx4{0.f, 0.f, 0.f, 0.f};

  for (int p = 0; p < 4; ++p) {
    floatx4 acc1[2][4];
#pragma unroll
    for (int a = 0; a < 2; ++a)
#pragma unroll
      for (int c = 0; c < 4; ++c) acc1[a][c] = floatx4{0.f, 0.f, 0.f, 0.f};
    const _Float16* A1 = W1h + (size_t)(128 * p + 32 * w + ml) * 128;
#pragma unroll
    for (int kk = 0; kk < 4; ++kk) {
      const int ko = kk * 32 + mq * 8;
      half8_t av0 = *(const half8_t*)(A1 + ko);
      half8_t av1 = *(const half8_t*)(A1 + 16 * 128 + ko);
#pragma unroll
      for (int nt = 0; nt < 4; ++nt) {
        half8_t bv = *(const half8_t*)&Hs[(nt * 16 + ml) * 136 + ko];
        acc1[0][nt] = mfma16(av0, bv, acc1[0][nt]);
        acc1[1][nt] = mfma16(av1, bv, acc1[1][nt]);
      }
    }
    __syncthreads();
#pragma unroll
    for (int mt = 0; mt < 2; ++mt) {
      const int kc = 32 * w + mt * 16 + mq * 4;
      floatx4 bv = *(const floatx4*)(b1 + 128 * p + kc);
#pragma unroll
      for (int nt = 0; nt < 4; ++nt) {
        half4_t hh;
#pragma unroll
        for (int r = 0; r < 4; ++r) {
          float v = acc1[mt][nt][r] + bv[r];
          hh[r] = (_Float16)(v > 0.f ? v : 0.f);
        }
        *(half4_t*)&H1s[(nt * 16 + ml) * 136 + kc] = hh;
      }
    }
    __syncthreads();
    const _Float16* A2 = W2h + (size_t)(64 * w + ml) * 512 + p * 128;
#pragma unroll
    for (int kk = 0; kk < 4; ++kk) {
      const int ko = kk * 32 + mq * 8;
#pragma unroll
      for (int nt = 0; nt < 4; ++nt) {
        half8_t bv = *(const half8_t*)&H1s[(nt * 16 + ml) * 136 + ko];
#pragma unroll
        for (int mt = 0; mt < 4; ++mt) {
          half8_t av = *(const half8_t*)(A2 + (size_t)(mt * 16) * 512 + ko);
          accO[mt][nt] = mfma16(av, bv, accO[mt][nt]);
        }
      }
    }
    __syncthreads();
  }

  _Float16* Ot = (_Float16*)(smem + 34816);  // [64][264] over scratch
#pragma unroll
  for (int mt = 0; mt < 4; ++mt) {
    const int m = 64 * w + mt * 16 + mq * 4;
    floatx4 bv = *(const floatx4*)(b2 + m);
#pragma unroll
    for (int nt = 0; nt < 4; ++nt) {
      const int n = nt * 16 + ml;
      half4_t hh;
#pragma unroll
      for (int r = 0; r < 4; ++r) hh[r] = (_Float16)(accO[mt][nt][r] + bv[r]);
      *(half4_t*)&Ot[n * 264 + m] = hh;
    }
  }
  __syncthreads();
#pragma unroll
  for (int it = 0; it < 8; ++it) {
    int i = it * 256 + tid;
    int n = i >> 5;
    int g = i & 31;
    int u = u0 + n;
    if (u >= GOODC) {
      half8_t v = *(const half8_t*)&Ot[n * 264 + g * 8];
      float* dst = outb + (size_t)(u - GOODC) * 256 + g * 8;
      floatx4 v0, v1;
#pragma unroll
      for (int tq = 0; tq < 4; ++tq) { v0[tq] = (float)v[tq]; v1[tq] = (float)v[4 + tq]; }
      *(floatx4*)dst = v0;
      *(floatx4*)(dst + 4) = v1;
    }
  }
  __syncthreads();  // scratch safe before next half
}

// ---------------- persistent dataflow kernel ---------------------------------
__global__ __launch_bounds__(256, 2) void mega_kernel(
    const float* __restrict__ inp, const _Float16* __restrict__ WIh,
    const float* __restrict__ bi, const _Float16* __restrict__ WFG,
    const _Float16* __restrict__ WRh, const float* __restrict__ bf,
    const float* __restrict__ bg, const float* __restrict__ br,
    const _Float16* __restrict__ W1h, const _Float16* __restrict__ W2h,
    const float* __restrict__ b1, const float* __restrict__ b2,
    _Float16* __restrict__ R0g, _Float16* __restrict__ Ph,
    _Float16* __restrict__ Qh, float* __restrict__ out) {
  __shared__ __align__(16) char smem[69632];
  __shared__ int s_j, s_bb, s_light;
  const int tid = threadIdx.x;

  // ---- startup: XCD self-assignment + bounded rendezvous ----
  if (tid == 0) {
    unsigned xcd;
    asm volatile("s_getreg_b32 %0, hwreg(HW_REG_XCC_ID)" : "=s"(xcd));
    xcd &= 7;
    int slot = __hip_atomic_fetch_add(&g_qhead[xcd], 1, __ATOMIC_RELAXED,
                                      __HIP_MEMORY_SCOPE_AGENT);
    __hip_atomic_fetch_add(&g_arrive, 1, __ATOMIC_RELEASE,
                           __HIP_MEMORY_SCOPE_AGENT);
    int ok = 1, it = 0;
    while (__hip_atomic_load(&g_arrive, __ATOMIC_ACQUIRE,
                             __HIP_MEMORY_SCOPE_AGENT) < NBLK) {
      if (++it > RDV_CAP) {
        ok = 0;
        __hip_atomic_store(&g_broken, 1, __ATOMIC_RELAXED,
                           __HIP_MEMORY_SCOPE_AGENT);
        break;
      }
      __builtin_amdgcn_s_sleep(8);
    }
    int light = ok;
    if (ok) {
#pragma unroll
      for (int x = 0; x < 8; ++x)
        light &= (__hip_atomic_load(&g_qhead[x], __ATOMIC_RELAXED,
                                    __HIP_MEMORY_SCOPE_AGENT) == NBLK / 8);
    }
    if (light) { s_bb = (int)xcd; s_j = slot; }
    else       { s_bb = blockIdx.x >> 6; s_j = blockIdx.x & 63; }
    s_light = light;
  }
  __syncthreads();
  const int j = s_j;
  const int bb = s_bb;
  const int light = s_light;
  const int u0 = j * TILE;

  _Float16* R0b = R0g + (size_t)bb * TT * HIDC;
  _Float16* Phb = Ph + (size_t)bb * TT * HIDC;
  _Float16* Qhb = Qh + (size_t)bb * TT * HIDC;
  const float* ib = inp + (size_t)bb * 256 * TT;
  float* outb = out + (size_t)bb * TGT * 256;
  int* myflag = &g_progress[bb * NTB + j];

#pragma unroll 1
  for (int q = 0; q < 22; ++q) {
    // ---- gate: 1 RAW producer + <=1 WAR reader ----
    if (q >= 1 && q <= 20) {
      const int dcur = 1 << ((q - 1) % 10);
      const int jraw = j - ((dcur + TILE - 1) >> 7);
      int jwar = -1;
      if (q >= 2) {
        const int dp = 1 << ((q - 2) % 10);
        int cand = j + ((dp + TILE - 1) >> 7);
        if (cand <= NTB - 1) jwar = cand;
      }
      if (tid == 0 && jraw >= 0) spin_tile(bb * NTB + jraw, q);
      if (tid == 1 && jwar >= 0) spin_tile(bb * NTB + jwar, q);
      __syncthreads();
      if (!light) __builtin_amdgcn_fence(__ATOMIC_ACQUIRE, "agent");
    }

    // ---- phase body ----
    if (q == 0) {
      input_half(ib, WIh, bi, R0b, Qhb, u0, 0, smem);
      input_half(ib, WIh, bi, R0b, Qhb, u0, 1, smem);
    } else if (q <= 20) {
      const int l = q - 1;
      const int d = 1 << (l % 10);
      const _Float16* pbin = ((q - 1) & 1) ? Phb : Qhb;
      _Float16* pbout = (q & 1) ? Phb : Qhb;
      int ext = 0;
      if (q <= 19) {
        ext = 1 << (q % 10);
        if (ext > TILE) ext = TILE;
      }
      phase_layer(pbin, pbout, WFG + (size_t)l * 65536,
                  WRh + (size_t)l * 16384, bf + l * 128, bg + l * 128,
                  br + l * 128, d, u0, ext, smem);
    } else {
      if (u0 + 127 >= GOODC) {
        if (u0 + 63 >= GOODC)
          head_half(R0b, W1h, W2h, b1, b2, outb, u0, 0, smem);
        head_half(R0b, W1h, W2h, b1, b2, outb, u0, 1, smem);
      }
    }

    // ---- release: r10-proven (vmcnt drain -> barrier -> LLC atomic flag) ----
    if (q <= 20) {
      if (light) {
        asm volatile("s_waitcnt vmcnt(0)" ::: "memory");  // data ack'd at L2
      } else {
        __builtin_amdgcn_fence(__ATOMIC_RELEASE, "agent");
      }
      __syncthreads();
      if (tid == 0)
        __hip_atomic_store(myflag, q + 1, __ATOMIC_RELAXED,
                           __HIP_MEMORY_SCOPE_AGENT);
    }
  }
}

extern "C" void kernel_launch(void* const* d_in, const int* in_sizes, int n_in,
                              void* d_out, int out_size, void* d_ws, size_t ws_size,
                              hipStream_t stream) {
  const float* inputs = (const float*)d_in[0];
  const float* Wi = (const float*)d_in[1];
  const float* bi = (const float*)d_in[2];
  const float* Wf = (const float*)d_in[3];
  const float* bf = (const float*)d_in[4];
  const float* Wg = (const float*)d_in[5];
  const float* bg = (const float*)d_in[6];
  const float* Wr = (const float*)d_in[7];
  const float* br = (const float*)d_in[8];
  const float* W1 = (const float*)d_in[9];
  const float* b1 = (const float*)d_in[10];
  const float* W2 = (const float*)d_in[11];
  const float* b2 = (const float*)d_in[12];
  float* out = (float*)d_out;

  // workspace (54 MB): R0g replaces the old ST slot (exactly 16 MB)
  char* ws = (char*)d_ws;
  _Float16* R0g = (_Float16*)(ws + 0);          // 8 x 8192 x 128 fp16 = 16 MB
  _Float16* Ph  = (_Float16*)(ws + 16777216);
  _Float16* Qh  = (_Float16*)(ws + 33554432);
  _Float16* WFG = (_Float16*)(ws + 50331648);
  _Float16* WRh = (_Float16*)(ws + 52953088);
  _Float16* WIh = (_Float16*)(ws + 53608448);
  _Float16* W1h = (_Float16*)(ws + 53673984);
  _Float16* W2h = (_Float16*)(ws + 53805056);

  prep_kernel<<<dim3(512), dim3(256), 0, stream>>>(Wi, Wf, Wg, Wr, W1, W2,
                                                   WIh, WFG, WRh, W1h, W2h);
  mega_kernel<<<dim3(NBLK), dim3(256), 0, stream>>>(
      inputs, WIh, bi, WFG, WRh, bf, bg, br, W1h, W2h, b1, b2,
      R0g, Ph, Qh, out);
}